// Round 9
// baseline (390.459 us; speedup 1.0000x reference)
//
#include <hip/hip_runtime.h>
#include <math.h>

#define B_ 8
#define T_ 1024
#define F_ 256
#define H_ 256
#define BT_ (B_*T_)          // 8192
constexpr float EPS = 1e-5f;
constexpr float SCALE = 0.0625f;   // 1/sqrt(256), folded into qbuf (exact pow2)

typedef unsigned int u32;
typedef unsigned short u16;
typedef __attribute__((ext_vector_type(8))) short bf16x8;    // 8 bf16 = 4 VGPRs
typedef __attribute__((ext_vector_type(4))) float f32x4;
typedef __attribute__((ext_vector_type(16))) float f32x16;

// ---------- bf16 helpers ----------
__device__ __forceinline__ float bf1(u16 p) { return __uint_as_float(((u32)p) << 16); }
__device__ __forceinline__ u16 f2bf(float f) {
  u32 u = __float_as_uint(f);
  u32 r = u + 0x7FFFu + ((u >> 16) & 1u);   // RNE
  return (u16)(r >> 16);
}

__device__ __forceinline__ f32x4 mfma16(bf16x8 a, bf16x8 b, f32x4 c) {
  return __builtin_amdgcn_mfma_f32_16x16x32_bf16(a, b, c, 0, 0, 0);
}
__device__ __forceinline__ f32x16 mfma32(bf16x8 a, bf16x8 b, f32x16 c) {
  return __builtin_amdgcn_mfma_f32_32x32x16_bf16(a, b, c, 0, 0, 0);
}

// async global->LDS, 16B per lane; dest = wave-uniform base + lane*16
__device__ __forceinline__ void gload_lds16(const u16* g, u16* l) {
  __builtin_amdgcn_global_load_lds(
      (const __attribute__((address_space(1))) u32*)(uintptr_t)g,
      (__attribute__((address_space(3))) u32*)(u32)(uintptr_t)l,
      16, 0, 0);
}

// ---------- block-wide reduction of 4 values over 256 threads ----------
__device__ __forceinline__ void block_reduce4(float& a, float& b, float& c, float& d) {
  #pragma unroll
  for (int off = 32; off > 0; off >>= 1) {
    a += __shfl_down(a, off, 64);
    b += __shfl_down(b, off, 64);
    c += __shfl_down(c, off, 64);
    d += __shfl_down(d, off, 64);
  }
  __shared__ float red[4][4];
  int wid = threadIdx.x >> 6;
  int lane = threadIdx.x & 63;
  if (lane == 0) { red[0][wid] = a; red[1][wid] = b; red[2][wid] = c; red[3][wid] = d; }
  __syncthreads();
  a = red[0][0] + red[0][1] + red[0][2] + red[0][3];
  b = red[1][0] + red[1][1] + red[1][2] + red[1][3];
  c = red[2][0] + red[2][1] + red[2][2] + red[2][3];
  d = red[3][0] + red[3][1] + red[3][2] + red[3][3];
}

// ---------- K1: LayerNorm over F per (b,t,plane); emit bf16 real/imag ----------
__global__ __launch_bounds__(256) void ln1_kernel(
    const float* __restrict__ x, const float* __restrict__ w, const float* __restrict__ bi,
    u16* __restrict__ xnr, u16* __restrict__ xni) {
  const int row = blockIdx.x;
  const int f = threadIdx.x;
  float2 xv = reinterpret_cast<const float2*>(x)[row * F_ + f];
  float sr = xv.x, si = xv.y, sr2 = xv.x * xv.x, si2 = xv.y * xv.y;
  block_reduce4(sr, si, sr2, si2);
  const float inv = 1.0f / F_;
  float mr = sr * inv, mi = si * inv;
  float vr = sr2 * inv - mr * mr, vi = si2 * inv - mi * mi;
  float rr = rsqrtf(vr + EPS), ri = rsqrtf(vi + EPS);
  float ww = w[f], bb = bi[f];
  xnr[row * F_ + f] = f2bf((xv.x - mr) * rr * ww + bb);
  xni[row * F_ + f] = f2bf((xv.y - mi) * ri * ww + bb);
}

// ---------- K2a: weight prep — transpose+convert W[z][f][h] (f32) -> wT[z][h][f] (bf16) ----------
__global__ __launch_bounds__(256) void wprep_kernel(
    const float* __restrict__ Wq, const float* __restrict__ Wk, const float* __restrict__ Wv,
    u16* __restrict__ wT) {
  const int z = blockIdx.z;
  const int m = z >> 3, n = z & 7;
  const float* W = (m == 0 ? Wq : (m == 1 ? Wk : Wv)) + (size_t)n * F_ * H_;
  const int ft = blockIdx.x * 64;
  const int ht = blockIdx.y * 64;
  __shared__ __align__(16) u16 Ts[64][72];

  const int tid = threadIdx.x;
  #pragma unroll
  for (int i = 0; i < 4; i++) {
    int id = tid + i * 256;
    int r = id >> 4, c4 = (id & 15) * 4;
    float4 p = *reinterpret_cast<const float4*>(&W[(size_t)(ft + r) * H_ + ht + c4]);
    Ts[r][c4 + 0] = f2bf(p.x); Ts[r][c4 + 1] = f2bf(p.y);
    Ts[r][c4 + 2] = f2bf(p.z); Ts[r][c4 + 3] = f2bf(p.w);
  }
  __syncthreads();
  u16* op = wT + (size_t)z * F_ * H_ + (size_t)ht * F_ + ft;
  #pragma unroll
  for (int i = 0; i < 2; i++) {
    int id = tid + i * 256;
    int hl = id & 63, g = id >> 6;
    u16 tmp[8];
    #pragma unroll
    for (int j = 0; j < 8; j++) tmp[j] = Ts[g * 8 + j][hl];
    *reinterpret_cast<uint4*>(op + (size_t)hl * F_ + g * 8) =
        *reinterpret_cast<const uint4*>(tmp);
  }
}

// ---------- K2b: QKV projections — bf16 MFMA GEMM, 128x256 tile (full H), BK=64 ----------
__global__ __launch_bounds__(256, 2) void qkv_kernel(
    const u16* __restrict__ xnr, const u16* __restrict__ xni, const u16* __restrict__ wT,
    const float* __restrict__ bq, const float* __restrict__ bk, const float* __restrict__ bv,
    u16* __restrict__ qo, u16* __restrict__ ko, u16* __restrict__ vTo) {
  const int z = blockIdx.y;
  const int m = z >> 3, n = z & 7;
  int sel; const float* bias; u16* out;
  if (m == 0)      { sel = (n >> 1) & 1;  bias = bq; out = qo + (size_t)n * BT_ * H_; }
  else if (m == 1) { sel = n & 1;         bias = bk; out = ko + (size_t)n * BT_ * H_; }
  else             { sel = __popc(n) & 1; bias = bv; out = nullptr; }
  const float osc = (m == 0) ? SCALE : 1.0f;
  const u16* A = sel ? xni : xnr;
  const u16* wp = wT + (size_t)z * F_ * H_;
  bias += n * H_;
  const int rowbase = blockIdx.x * 128;

  __shared__ __align__(16) u16 As[2][128 * 32];   // 16 KB
  __shared__ __align__(16) u16 Bs[2][256 * 32];   // 32 KB
  __shared__ __align__(16) u16 Epi[4][1536];      // q/k: [16][72]; v: [64][24]

  const int tid = threadIdx.x;
  const int wv = tid >> 6, lane = tid & 63;
  const int quad = lane >> 4, l16 = lane & 15;
  const int wrow = wv >> 1, wcol = wv & 1;        // wave: 64 rows x 128 cols

  f32x4 acc[4][8];
  #pragma unroll
  for (int i = 0; i < 4; i++)
    #pragma unroll
    for (int j = 0; j < 8; j++) acc[i][j] = (f32x4){0.f, 0.f, 0.f, 0.f};

  const int ar = tid >> 2;            // A staging: row tid>>2, k-chunk (tid&3)*8
  const int ak = (tid & 3) * 8;

  #pragma unroll 1
  for (int kb = 0; kb < F_; kb += 64) {
    #pragma unroll
    for (int h = 0; h < 2; h++) {
      // A half: 128x32 = 8KB = 2 DMA groups
      gload_lds16(A + (size_t)(rowbase + ar) * F_ + kb + h * 32 + ak,
                  &As[h][tid * 8]);
      gload_lds16(A + (size_t)(rowbase + 64 + ar) * F_ + kb + h * 32 + ak,
                  &As[h][2048 + tid * 8]);
      // B half: 256x32 = 16KB = 4 DMA groups
      #pragma unroll
      for (int c = 0; c < 4; c++)
        gload_lds16(wp + (size_t)(c * 64 + ar) * F_ + kb + h * 32 + ak,
                    &Bs[h][c * 2048 + tid * 8]);
    }
    __syncthreads();
    #pragma unroll
    for (int h = 0; h < 2; h++) {
      bf16x8 a[4], b[8];
      #pragma unroll
      for (int mi = 0; mi < 4; mi++)
        a[mi] = *reinterpret_cast<const bf16x8*>(
            &As[h][(wrow * 64 + mi * 16 + l16) * 32 + quad * 8]);
      #pragma unroll
      for (int nj = 0; nj < 8; nj++)
        b[nj] = *reinterpret_cast<const bf16x8*>(
            &Bs[h][(wcol * 128 + nj * 16 + l16) * 32 + quad * 8]);
      #pragma unroll
      for (int mi = 0; mi < 4; mi++)
        #pragma unroll
        for (int nj = 0; nj < 8; nj++)
          acc[mi][nj] = mfma16(a[mi], b[nj], acc[mi][nj]);
    }
    __syncthreads();
  }

  float bias8[8];
  #pragma unroll
  for (int nj = 0; nj < 8; nj++)
    bias8[nj] = bias[wcol * 128 + nj * 16 + l16];

  if (m != 2) {   // q/k: row-major store, two 64-col passes
    #pragma unroll
    for (int pass = 0; pass < 2; pass++) {
      #pragma unroll
      for (int mi = 0; mi < 4; mi++) {
        #pragma unroll
        for (int nj4 = 0; nj4 < 4; nj4++) {
          int nj = pass * 4 + nj4;
          #pragma unroll
          for (int r = 0; r < 4; r++)
            Epi[wv][(quad * 4 + r) * 72 + nj4 * 16 + l16] =
                f2bf((acc[mi][nj][r] + bias8[nj]) * osc);
        }
        int row = rowbase + wrow * 64 + mi * 16 + l16;
        uint4 v0 = *reinterpret_cast<const uint4*>(&Epi[wv][l16 * 72 + quad * 16]);
        uint4 v1 = *reinterpret_cast<const uint4*>(&Epi[wv][l16 * 72 + quad * 16 + 8]);
        u16* op = out + (size_t)row * H_ + wcol * 128 + pass * 64 + quad * 16;
        *reinterpret_cast<uint4*>(op) = v0;
        *reinterpret_cast<uint4*>(op + 8) = v1;
      }
    }
  } else {        // v: transposed store into vT[n][h][bt], two 64-h passes
    #pragma unroll
    for (int pass = 0; pass < 2; pass++) {
      #pragma unroll
      for (int mi = 0; mi < 4; mi++) {
        #pragma unroll
        for (int nj4 = 0; nj4 < 4; nj4++) {
          int nj = pass * 4 + nj4;
          #pragma unroll
          for (int r = 0; r < 4; r++)
            Epi[wv][(nj4 * 16 + l16) * 24 + quad * 4 + r] =
                f2bf(acc[mi][nj][r] + bias8[nj]);
        }
        int hloc = lane;                  // 0..63
        uint4 w0 = *reinterpret_cast<const uint4*>(&Epi[wv][hloc * 24]);
        uint4 w1 = *reinterpret_cast<const uint4*>(&Epi[wv][hloc * 24 + 8]);
        u16* op = vTo + (size_t)n * H_ * BT_ +
                  (size_t)(wcol * 128 + pass * 64 + hloc) * BT_ +
                  rowbase + wrow * 64 + mi * 16;
        *reinterpret_cast<uint4*>(op) = w0;
        *reinterpret_cast<uint4*>(op + 8) = w1;
      }
    }
  }
}

// ---------- K3: MFMA flash attention ----------
// R18 == R17 resubmitted (R17 bench died on an unresponsive container; no
// data). R16 with __launch_bounds__(512, 1): R16's (512,2) capped the
// register allocator at 128 VGPRs while the merged M-phase needs ~180 live
// -> scratch spills (FETCH 82->749 MB, WRITE 32->125 MB, 3x slowdown). LDS
// is 149.5 KB so the HW fits only 1 block/CU anyway: (,2) bought nothing and
// cost 128 VGPRs of headroom. (,1) -> up to 256 VGPRs, no spill, same
// occupancy. Everything else identical to R16.
__global__ __launch_bounds__(512, 1) void attn_kernel(
    const u16* __restrict__ q, const u16* __restrict__ k, const u16* __restrict__ vT,
    u16* __restrict__ obuf) {
  const int fid = blockIdx.x;        // 0..511
  const int qt = fid >> 6;           // 0..7 : 128 query rows
  const int nb = fid & 63;           // n*8 + b ; XCD = nb & 7
  const int n = nb >> 3, b = nb & 7;
  const int tid = threadIdx.x;
  const int wv = tid >> 6, lane = tid & 63;
  const int hi = lane >> 5, l32 = lane & 31;
  const int qh = wv >> 1;            // q 32-row group (0..3)
  const int kh = wv & 1;             // QK: key-half (32 keys)
  const int hh = wv & 1;             // PV: h-half (128 h)

  const size_t base = (size_t)nb * T_ * H_;
  const u16* qp = q + base;          // pre-scaled by SCALE
  const u16* kp = k + base;
  const u16* vtp = vT + ((size_t)n * H_ * B_ + b) * T_;

  __shared__ __align__(16) u16 Ks[2][64][256];   // 64 KB, 5-bit XOR swizzle
  __shared__ __align__(16) u16 Vs[2][64][256];   // 64 KB, packed-4h + 3-bit XOR
  __shared__ __align__(16) u16 Ps[4][32][72];    // 18,432 B (cols 64..67: l-sums)

  const int qrow0 = qt * 128 + qh * 32;
  bf16x8 qf[16];
  #pragma unroll
  for (int kc = 0; kc < 16; kc++)
    qf[kc] = *reinterpret_cast<const bf16x8*>(
        qp + (size_t)(qrow0 + l32) * H_ + kc * 16 + hi * 8);

  f32x16 o[4];
  #pragma unroll
  for (int ot = 0; ot < 4; ot++)
    #pragma unroll
    for (int r = 0; r < 16; r++) o[ot][r] = 0.f;
  float lper[16];
  #pragma unroll
  for (int r = 0; r < 16; r++) lper[r] = 0.f;

  // K staging: 32 DMA instrs (4/wave), each fills 2 rows (512B each).
  // Lane l -> row 2*idx+(l>>5), 16B slot (l&31). Slot s of row r holds
  // K[r][(s ^ (r&31))*8 ..], so source col = ((l&31) ^ (row&31))*8.
  auto stage_k = [&](int ktN, int buf) {
    #pragma unroll
    for (int i = 0; i < 4; i++) {
      int idx = wv * 4 + i;
      int row = 2 * idx + hi;
      const u16* src = kp + (size_t)(ktN * 64 + row) * H_ +
                       ((l32 ^ (row & 31)) * 8);
      gload_lds16(src, &Ks[buf][2 * idx][0]);
    }
  };
  // V staging: 32 DMA instrs (4/wave), each fills 2 physical rows.
  // Physical row p holds h = p*4..p*4+3 (64 keys each). Slot s of row p
  // holds unswizzled block u = s ^ (p&7); u -> h = p*4 + (u>>3),
  // key0 = (u&7)*8.  Lane l: p = 2*idx+(l>>5), s = l&31.
  auto stage_v = [&](int ktN, int buf) {
    #pragma unroll
    for (int i = 0; i < 4; i++) {
      int idx = wv * 4 + i;
      int p = 2 * idx + hi;
      int u = l32 ^ (p & 7);
      const u16* src = vtp + (size_t)(p * 4 + (u >> 3)) * BT_ +
                       ktN * 64 + (u & 7) * 8;
      gload_lds16(src, &Vs[buf][2 * idx][0]);
    }
  };

  // Prologue: stage tiles 0,1 (order K0,V0,K1,V1); wait K0 only.
  stage_k(0, 0); stage_v(0, 0);
  stage_k(1, 1); stage_v(1, 1);
  asm volatile("s_waitcnt vmcnt(12)" ::: "memory");
  __builtin_amdgcn_s_barrier();
  __builtin_amdgcn_sched_barrier(0);

  const int krow = kh * 32 + l32;

  // QK(0) from Ks[0]
  f32x16 sa, sb;
  #pragma unroll
  for (int r = 0; r < 16; r++) { sa[r] = 0.f; sb[r] = 0.f; }
  __builtin_amdgcn_s_setprio(1);
  #pragma unroll
  for (int kc = 0; kc < 16; kc += 2) {
    bf16x8 kfa = *reinterpret_cast<const bf16x8*>(
        &Ks[0][krow][(((kc * 2 + hi) ^ l32) * 8)]);
    bf16x8 kfb = *reinterpret_cast<const bf16x8*>(
        &Ks[0][krow][(((kc * 2 + 2 + hi) ^ l32) * 8)]);
    sa = mfma32(qf[kc], kfa, sa);
    sb = mfma32(qf[kc + 1], kfb, sb);
  }
  __builtin_amdgcn_s_setprio(0);

  // Retire Ks[0] reads across ALL waves, then overwrite buf0 with K2.
  asm volatile("s_waitcnt lgkmcnt(0)" ::: "memory");
  __builtin_amdgcn_s_barrier();
  __builtin_amdgcn_sched_barrier(0);
  stage_k(2, 0);

  // softmax(0) -> Ps
  #pragma unroll
  for (int r = 0; r < 16; r++) {
    float p = __expf(sa[r] + sb[r]);
    lper[r] += p;
    Ps[qh][(r & 3) + 8 * (r >> 2) + 4 * hi][kh * 32 + l32] = f2bf(p);
  }
  asm volatile("s_waitcnt lgkmcnt(0)" ::: "memory");
  asm volatile("s_waitcnt vmcnt(8)" ::: "memory");   // V0,K1 done; V1,K2 fly
  __builtin_amdgcn_s_barrier();
  __builtin_amdgcn_sched_barrier(0);

  #pragma unroll 1
  for (int kt = 0; kt < 16; kt++) {
    const int cv = kt & 1;            // Vs buffer of tile kt
    const int ck = (kt + 1) & 1;      // Ks buffer of tile kt+1

    // ---- M(kt): PV(kt) + QK(kt+1), one MFMA cluster, 6 chains
    bf16x8 pa[4];
    #pragma unroll
    for (int kc2 = 0; kc2 < 4; kc2++)
      pa[kc2] = *reinterpret_cast<const bf16x8*>(
          &Ps[qh][l32][kc2 * 16 + hi * 8]);

    if (kt < 15) {
      #pragma unroll
      for (int r = 0; r < 16; r++) { sa[r] = 0.f; sb[r] = 0.f; }
      __builtin_amdgcn_s_setprio(1);
      #pragma unroll
      for (int g = 0; g < 4; g++) {
        const int p = hh * 32 + g * 8 + (l32 >> 2);
        #pragma unroll
        for (int kc2 = 0; kc2 < 4; kc2++) {
          int s = ((l32 & 3) * 8 + kc2 * 2 + hi) ^ (l32 >> 2);
          bf16x8 vf = *reinterpret_cast<const bf16x8*>(&Vs[cv][p][s * 8]);
          o[g] = mfma32(pa[kc2], vf, o[g]);
        }
        const int kc = g * 4;
        bf16x8 k0 = *reinterpret_cast<const bf16x8*>(
            &Ks[ck][krow][((((kc + 0) * 2 + hi) ^ l32) * 8)]);
        bf16x8 k1 = *reinterpret_cast<const bf16x8*>(
            &Ks[ck][krow][((((kc + 1) * 2 + hi) ^ l32) * 8)]);
        bf16x8 k2 = *reinterpret_cast<const bf16x8*>(
            &Ks[ck][krow][((((kc + 2) * 2 + hi) ^ l32) * 8)]);
        bf16x8 k3 = *reinterpret_cast<const bf16x8*>(
            &Ks[ck][krow][((((kc + 3) * 2 + hi) ^ l32) * 8)]);
        sa = mfma32(qf[kc + 0], k0, sa);
        sb = mfma32(qf[kc + 1], k1, sb);
        sa = mfma32(qf[kc + 2], k2, sa);
        sb = mfma32(qf[kc + 3], k3, sb);
      }
      __builtin_amdgcn_s_setprio(0);
    } else {
      __builtin_amdgcn_s_setprio(1);
      #pragma unroll
      for (int g = 0; g < 4; g++) {
        const int p = hh * 32 + g * 8 + (l32 >> 2);
        #pragma unroll
        for (int kc2 = 0; kc2 < 4; kc2++) {
          int s = ((l32 & 3) * 8 + kc2 * 2 + hi) ^ (l32 >> 2);
          bf16x8 vf = *reinterpret_cast<const bf16x8*>(&Vs[cv][p][s * 8]);
          o[g] = mfma32(pa[kc2], vf, o[g]);
        }
      }
      __builtin_amdgcn_s_setprio(0);
    }

    // ---- B1: all waves' M(kt) LDS reads retired (Ks[ck], Vs[cv], Ps)
    asm volatile("s_waitcnt lgkmcnt(0)" ::: "memory");
    __builtin_amdgcn_s_barrier();
    __builtin_amdgcn_sched_barrier(0);

    // Stage 2 tiles ahead into the buffers freed at B1.
    if (kt <= 12) stage_k(kt + 3, ck);   // (kt+3)&1 == ck
    if (kt <= 13) stage_v(kt + 2, cv);   // (kt+2)&1 == cv

    // ---- SM(kt): softmax(kt+1), VALU-only + Ps write
    if (kt < 15) {
      #pragma unroll
      for (int r = 0; r < 16; r++) {
        float pp = __expf(sa[r] + sb[r]);
        lper[r] += pp;
        Ps[qh][(r & 3) + 8 * (r >> 2) + 4 * hi][kh * 32 + l32] = f2bf(pp);
      }
      // ---- B2: Ps(kt+1) visible; K(kt+2)/V(kt+1) (for M(kt+1)) landed.
      asm volatile("s_waitcnt lgkmcnt(0)" ::: "memory");
      if (kt <= 12)      asm volatile("s_waitcnt vmcnt(8)" ::: "memory");
      else if (kt == 13) asm volatile("s_waitcnt vmcnt(4)" ::: "memory");
      else               asm volatile("s_waitcnt vmcnt(0)" ::: "memory");
      __builtin_amdgcn_s_barrier();
      __builtin_amdgcn_sched_barrier(0);
    }
  }

  #pragma unroll
  for (int r = 0; r < 16; r++) {
    #pragma unroll
    for (int off = 1; off < 32; off <<= 1)
      lper[r] += __shfl_xor(lper[r], off, 64);
  }
  if (l32 == 0) {
    #pragma unroll
    for (int r = 0; r < 16; r++) {
      int row = (r & 3) + 8 * (r >> 2) + 4 * hi;
      *reinterpret_cast<float*>(&Ps[qh][row][64 + 2 * kh]) = lper[r];
    }
  }
  __syncthreads();

  float invl[16];
  #pragma unroll
  for (int r = 0; r < 16; r++) {
    int row = (r & 3) + 8 * (r >> 2) + 4 * hi;
    float l0 = *reinterpret_cast<const float*>(&Ps[qh][row][64]);
    float l1 = *reinterpret_cast<const float*>(&Ps[qh][row][66]);
    invl[r] = 1.0f / (l0 + l1);
  }

  u16* Ew = reinterpret_cast<u16*>(&Ks[0][0][0]) + wv * 1280;   // 8x1280 u16
  const int grow = b * 1024 + qrow0 + l32;
  #pragma unroll
  for (int ot = 0; ot < 4; ot++) {
    #pragma unroll
    for (int r = 0; r < 16; r++) {
      int row = (r & 3) + 8 * (r >> 2) + 4 * hi;
      Ew[row * 40 + l32] = f2bf(o[ot][r] * invl[r]);
    }
    int ht = hh * 4 + ot;
    uint4 v0 = *reinterpret_cast<const uint4*>(&Ew[l32 * 40 + hi * 16]);
    uint4 v1 = *reinterpret_cast<const uint4*>(&Ew[l32 * 40 + hi * 16 + 8]);
    u16* op = obuf + (((size_t)n * 8 + ht) * BT_ + grow) * 32 + hi * 16;
    *reinterpret_cast<uint4*>(op) = v0;
    *reinterpret_cast<uint4*>(op + 8) = v1;
  }
}

// ---------- K4: combine 8 branches (signed) + LayerNorm over H ----------
__global__ __launch_bounds__(256) void combine_ln2_kernel(
    const u16* __restrict__ obuf, const float* __restrict__ w,
    const float* __restrict__ bi, float* __restrict__ out) {
  const int row = blockIdx.x;
  const int h = threadIdx.x;
  float o[8];
  #pragma unroll
  for (int nn = 0; nn < 8; nn++)
    o[nn] = bf1(obuf[(((size_t)nn * 8 + (h >> 5)) * BT_ + row) * 32 + (h & 31)]);
  float re = o[0] - o[1] - o[2] - o[3];
  float im = o[4] + o[5] + o[6] - o[7];
  float sr = re, si = im, sr2 = re * re, si2 = im * im;
  block_reduce4(sr, si, sr2, si2);
  const float inv = 1.0f / H_;
  float mr = sr * inv, mi = si * inv;
  float vr = sr2 * inv - mr * mr, vi = si2 * inv - mi * mi;
  float rr = rsqrtf(vr + EPS), ri = rsqrtf(vi + EPS);
  float ww = w[h], bb = bi[h];
  float2 res;
  res.x = (re - mr) * rr * ww + bb;
  res.y = (im - mi) * ri * ww + bb;
  reinterpret_cast<float2*>(out)[(size_t)row * H_ + h] = res;
}

extern "C" void kernel_launch(void* const* d_in, const int* in_sizes, int n_in,
                              void* d_out, int out_size, void* d_ws, size_t ws_size,
                              hipStream_t stream) {
  const float* x    = (const float*)d_in[0];
  const float* Wq   = (const float*)d_in[1];
  const float* bq   = (const float*)d_in[2];
  const float* Wk   = (const float*)d_in[3];
  const float* bk   = (const float*)d_in[4];
  const float* Wv   = (const float*)d_in[5];
  const float* bv   = (const float*)d_in[6];
  const float* ln1w = (const float*)d_in[7];
  const float* ln1b = (const float*)d_in[8];
  const float* ln2w = (const float*)d_in[9];
  const float* ln2b = (const float*)d_in[10];

  // Workspace (128 MB), lifetime-aliased:
  //  [0,8)  xn  (dead after qkv)  |  [0,32)  obuf (written by attn, after qkv)
  //  [8,11) wT  (dead after qkv)
  //  [32,64) vT ; [64,96) q ; [96,128) k
  char* ws = (char*)d_ws;
  u16* xnr  = (u16*)(ws);
  u16* xni  = (u16*)(ws + (4ull  << 20));
  u16* wTb  = (u16*)(ws + (8ull  << 20));
  u16* obuf = (u16*)(ws);
  u16* vT   = (u16*)(ws + (32ull << 20));
  u16* qbuf = (u16*)(ws + (64ull << 20));
  u16* kbuf = (u16*)(ws + (96ull << 20));

  ln1_kernel<<<BT_, 256, 0, stream>>>(x, ln1w, ln1b, xnr, xni);
  wprep_kernel<<<dim3(4, 4, 24), 256, 0, stream>>>(Wq, Wk, Wv, wTb);
  qkv_kernel<<<dim3(64, 24), 256, 0, stream>>>(xnr, xni, wTb, bq, bk, bv,
                                               qbuf, kbuf, vT);
  attn_kernel<<<dim3(512), 512, 0, stream>>>(qbuf, kbuf, vT, obuf);
  combine_ln2_kernel<<<BT_, 256, 0, stream>>>(obuf, ln2w, ln2b, (float*)d_out);
}

// Round 11
// 176.086 us; speedup vs baseline: 2.2174x; 2.2174x over previous
//
#include <hip/hip_runtime.h>
#include <math.h>

#define B_ 8
#define T_ 1024
#define F_ 256
#define H_ 256
#define BT_ (B_*T_)          // 8192
constexpr float EPS = 1e-5f;
// 1/sqrt(256) * log2(e), folded into qbuf: softmax then uses exp2 directly.
constexpr float SCALE_L2E = 0.09016844005555963f;

typedef unsigned int u32;
typedef unsigned short u16;
typedef __attribute__((ext_vector_type(8))) short bf16x8;    // 8 bf16 = 4 VGPRs
typedef __attribute__((ext_vector_type(4))) float f32x4;
typedef __attribute__((ext_vector_type(16))) float f32x16;

// ---------- bf16 helpers ----------
__device__ __forceinline__ float bf1(u16 p) { return __uint_as_float(((u32)p) << 16); }
__device__ __forceinline__ u16 f2bf(float f) {
  u32 u = __float_as_uint(f);
  u32 r = u + 0x7FFFu + ((u >> 16) & 1u);   // RNE
  return (u16)(r >> 16);
}

__device__ __forceinline__ f32x4 mfma16(bf16x8 a, bf16x8 b, f32x4 c) {
  return __builtin_amdgcn_mfma_f32_16x16x32_bf16(a, b, c, 0, 0, 0);
}
__device__ __forceinline__ f32x16 mfma32(bf16x8 a, bf16x8 b, f32x16 c) {
  return __builtin_amdgcn_mfma_f32_32x32x16_bf16(a, b, c, 0, 0, 0);
}

// async global->LDS, 16B per lane; dest = wave-uniform base + lane*16
__device__ __forceinline__ void gload_lds16(const u16* g, u16* l) {
  __builtin_amdgcn_global_load_lds(
      (const __attribute__((address_space(1))) u32*)(uintptr_t)g,
      (__attribute__((address_space(3))) u32*)(u32)(uintptr_t)l,
      16, 0, 0);
}

// ---------- block-wide reduction of 4 values over 256 threads ----------
__device__ __forceinline__ void block_reduce4(float& a, float& b, float& c, float& d) {
  #pragma unroll
  for (int off = 32; off > 0; off >>= 1) {
    a += __shfl_down(a, off, 64);
    b += __shfl_down(b, off, 64);
    c += __shfl_down(c, off, 64);
    d += __shfl_down(d, off, 64);
  }
  __shared__ float red[4][4];
  int wid = threadIdx.x >> 6;
  int lane = threadIdx.x & 63;
  if (lane == 0) { red[0][wid] = a; red[1][wid] = b; red[2][wid] = c; red[3][wid] = d; }
  __syncthreads();
  a = red[0][0] + red[0][1] + red[0][2] + red[0][3];
  b = red[1][0] + red[1][1] + red[1][2] + red[1][3];
  c = red[2][0] + red[2][1] + red[2][2] + red[2][3];
  d = red[3][0] + red[3][1] + red[3][2] + red[3][3];
}

// ---------- K1: LayerNorm over F per (b,t,plane); emit bf16 real/imag ----------
__global__ __launch_bounds__(256) void ln1_kernel(
    const float* __restrict__ x, const float* __restrict__ w, const float* __restrict__ bi,
    u16* __restrict__ xnr, u16* __restrict__ xni) {
  const int row = blockIdx.x;
  const int f = threadIdx.x;
  float2 xv = reinterpret_cast<const float2*>(x)[row * F_ + f];
  float sr = xv.x, si = xv.y, sr2 = xv.x * xv.x, si2 = xv.y * xv.y;
  block_reduce4(sr, si, sr2, si2);
  const float inv = 1.0f / F_;
  float mr = sr * inv, mi = si * inv;
  float vr = sr2 * inv - mr * mr, vi = si2 * inv - mi * mi;
  float rr = rsqrtf(vr + EPS), ri = rsqrtf(vi + EPS);
  float ww = w[f], bb = bi[f];
  xnr[row * F_ + f] = f2bf((xv.x - mr) * rr * ww + bb);
  xni[row * F_ + f] = f2bf((xv.y - mi) * ri * ww + bb);
}

// ---------- K2a: weight prep — transpose+convert W[z][f][h] (f32) -> wT[z][h][f] (bf16) ----------
__global__ __launch_bounds__(256) void wprep_kernel(
    const float* __restrict__ Wq, const float* __restrict__ Wk, const float* __restrict__ Wv,
    u16* __restrict__ wT) {
  const int z = blockIdx.z;
  const int m = z >> 3, n = z & 7;
  const float* W = (m == 0 ? Wq : (m == 1 ? Wk : Wv)) + (size_t)n * F_ * H_;
  const int ft = blockIdx.x * 64;
  const int ht = blockIdx.y * 64;
  __shared__ __align__(16) u16 Ts[64][72];

  const int tid = threadIdx.x;
  #pragma unroll
  for (int i = 0; i < 4; i++) {
    int id = tid + i * 256;
    int r = id >> 4, c4 = (id & 15) * 4;
    float4 p = *reinterpret_cast<const float4*>(&W[(size_t)(ft + r) * H_ + ht + c4]);
    Ts[r][c4 + 0] = f2bf(p.x); Ts[r][c4 + 1] = f2bf(p.y);
    Ts[r][c4 + 2] = f2bf(p.z); Ts[r][c4 + 3] = f2bf(p.w);
  }
  __syncthreads();
  u16* op = wT + (size_t)z * F_ * H_ + (size_t)ht * F_ + ft;
  #pragma unroll
  for (int i = 0; i < 2; i++) {
    int id = tid + i * 256;
    int hl = id & 63, g = id >> 6;
    u16 tmp[8];
    #pragma unroll
    for (int j = 0; j < 8; j++) tmp[j] = Ts[g * 8 + j][hl];
    *reinterpret_cast<uint4*>(op + (size_t)hl * F_ + g * 8) =
        *reinterpret_cast<const uint4*>(tmp);
  }
}

// ---------- K2b: QKV projections — bf16 MFMA GEMM, 128x256 tile (full H), BK=64 ----------
__global__ __launch_bounds__(256, 2) void qkv_kernel(
    const u16* __restrict__ xnr, const u16* __restrict__ xni, const u16* __restrict__ wT,
    const float* __restrict__ bq, const float* __restrict__ bk, const float* __restrict__ bv,
    u16* __restrict__ qo, u16* __restrict__ ko, u16* __restrict__ vTo) {
  const int z = blockIdx.y;
  const int m = z >> 3, n = z & 7;
  int sel; const float* bias; u16* out;
  if (m == 0)      { sel = (n >> 1) & 1;  bias = bq; out = qo + (size_t)n * BT_ * H_; }
  else if (m == 1) { sel = n & 1;         bias = bk; out = ko + (size_t)n * BT_ * H_; }
  else             { sel = __popc(n) & 1; bias = bv; out = nullptr; }
  const float osc = (m == 0) ? SCALE_L2E : 1.0f;   // q pre-scaled by 1/16*log2(e)
  const u16* A = sel ? xni : xnr;
  const u16* wp = wT + (size_t)z * F_ * H_;
  bias += n * H_;
  const int rowbase = blockIdx.x * 128;

  __shared__ __align__(16) u16 As[2][128 * 32];   // 16 KB
  __shared__ __align__(16) u16 Bs[2][256 * 32];   // 32 KB
  __shared__ __align__(16) u16 Epi[4][1536];      // q/k: [16][72]; v: [64][24]

  const int tid = threadIdx.x;
  const int wv = tid >> 6, lane = tid & 63;
  const int quad = lane >> 4, l16 = lane & 15;
  const int wrow = wv >> 1, wcol = wv & 1;        // wave: 64 rows x 128 cols

  f32x4 acc[4][8];
  #pragma unroll
  for (int i = 0; i < 4; i++)
    #pragma unroll
    for (int j = 0; j < 8; j++) acc[i][j] = (f32x4){0.f, 0.f, 0.f, 0.f};

  const int ar = tid >> 2;            // A staging: row tid>>2, k-chunk (tid&3)*8
  const int ak = (tid & 3) * 8;

  #pragma unroll 1
  for (int kb = 0; kb < F_; kb += 64) {
    #pragma unroll
    for (int h = 0; h < 2; h++) {
      // A half: 128x32 = 8KB = 2 DMA groups
      gload_lds16(A + (size_t)(rowbase + ar) * F_ + kb + h * 32 + ak,
                  &As[h][tid * 8]);
      gload_lds16(A + (size_t)(rowbase + 64 + ar) * F_ + kb + h * 32 + ak,
                  &As[h][2048 + tid * 8]);
      // B half: 256x32 = 16KB = 4 DMA groups
      #pragma unroll
      for (int c = 0; c < 4; c++)
        gload_lds16(wp + (size_t)(c * 64 + ar) * F_ + kb + h * 32 + ak,
                    &Bs[h][c * 2048 + tid * 8]);
    }
    __syncthreads();
    #pragma unroll
    for (int h = 0; h < 2; h++) {
      bf16x8 a[4], b[8];
      #pragma unroll
      for (int mi = 0; mi < 4; mi++)
        a[mi] = *reinterpret_cast<const bf16x8*>(
            &As[h][(wrow * 64 + mi * 16 + l16) * 32 + quad * 8]);
      #pragma unroll
      for (int nj = 0; nj < 8; nj++)
        b[nj] = *reinterpret_cast<const bf16x8*>(
            &Bs[h][(wcol * 128 + nj * 16 + l16) * 32 + quad * 8]);
      #pragma unroll
      for (int mi = 0; mi < 4; mi++)
        #pragma unroll
        for (int nj = 0; nj < 8; nj++)
          acc[mi][nj] = mfma16(a[mi], b[nj], acc[mi][nj]);
    }
    __syncthreads();
  }

  float bias8[8];
  #pragma unroll
  for (int nj = 0; nj < 8; nj++)
    bias8[nj] = bias[wcol * 128 + nj * 16 + l16];

  if (m != 2) {   // q/k: row-major store, two 64-col passes
    #pragma unroll
    for (int pass = 0; pass < 2; pass++) {
      #pragma unroll
      for (int mi = 0; mi < 4; mi++) {
        #pragma unroll
        for (int nj4 = 0; nj4 < 4; nj4++) {
          int nj = pass * 4 + nj4;
          #pragma unroll
          for (int r = 0; r < 4; r++)
            Epi[wv][(quad * 4 + r) * 72 + nj4 * 16 + l16] =
                f2bf((acc[mi][nj][r] + bias8[nj]) * osc);
        }
        int row = rowbase + wrow * 64 + mi * 16 + l16;
        uint4 v0 = *reinterpret_cast<const uint4*>(&Epi[wv][l16 * 72 + quad * 16]);
        uint4 v1 = *reinterpret_cast<const uint4*>(&Epi[wv][l16 * 72 + quad * 16 + 8]);
        u16* op = out + (size_t)row * H_ + wcol * 128 + pass * 64 + quad * 16;
        *reinterpret_cast<uint4*>(op) = v0;
        *reinterpret_cast<uint4*>(op + 8) = v1;
      }
    }
  } else {        // v: transposed store into vT[n][h][bt], two 64-h passes
    #pragma unroll
    for (int pass = 0; pass < 2; pass++) {
      #pragma unroll
      for (int mi = 0; mi < 4; mi++) {
        #pragma unroll
        for (int nj4 = 0; nj4 < 4; nj4++) {
          int nj = pass * 4 + nj4;
          #pragma unroll
          for (int r = 0; r < 4; r++)
            Epi[wv][(nj4 * 16 + l16) * 24 + quad * 4 + r] =
                f2bf(acc[mi][nj][r] + bias8[nj]);
        }
        int hloc = lane;                  // 0..63
        uint4 w0 = *reinterpret_cast<const uint4*>(&Epi[wv][hloc * 24]);
        uint4 w1 = *reinterpret_cast<const uint4*>(&Epi[wv][hloc * 24 + 8]);
        u16* op = vTo + (size_t)n * H_ * BT_ +
                  (size_t)(wcol * 128 + pass * 64 + hloc) * BT_ +
                  rowbase + wrow * 64 + mi * 16;
        *reinterpret_cast<uint4*>(op) = w0;
        *reinterpret_cast<uint4*>(op + 8) = w1;
      }
    }
  }
}

// ---------- K3: MFMA flash attention ----------
// R20 == R19 with the compile fix: exp2f (HIP device) not __exp2f (CUDA-ism).
// R14 revert (best measured: attn 103.4 us, total 172.7 us, no spill)
// + exp2 fold (log2e folded into q pre-scale; softmax uses exp2f -> single
// v_exp_f32, no range-reduction mul).
// Merged-pipeline arc (R15-R18) closed: PV+QK merge spills at any bounds
// (H=256 forces 64 accum regs; qf cannot stay live across both phases).
// Schedule (counted vmcnt, split K/V prefetch, distance ~1 iter each):
//   QK(kt) | softmax | B1(lgkm0) | stage_k(kt+2,c) | PV(kt) |
//   B2(vmcnt 4/0) | stage_v(kt+2,c)
// Swizzles: K 5-bit XOR (read block (kc*2+hi)^l32 -> 32 distinct slots);
// V packed-4h [64][256] 3-bit XOR (slot ((l32&3)*8+kc2*2+hi)^(l32>>2)).
__global__ __launch_bounds__(512, 2) void attn_kernel(
    const u16* __restrict__ q, const u16* __restrict__ k, const u16* __restrict__ vT,
    u16* __restrict__ obuf) {
  const int fid = blockIdx.x;        // 0..511
  const int qt = fid >> 6;           // 0..7 : 128 query rows
  const int nb = fid & 63;           // n*8 + b ; XCD = nb & 7
  const int n = nb >> 3, b = nb & 7;
  const int tid = threadIdx.x;
  const int wv = tid >> 6, lane = tid & 63;
  const int hi = lane >> 5, l32 = lane & 31;
  const int qh = wv >> 1;            // q 32-row group (0..3)
  const int kh = wv & 1;             // QK: key-half (32 keys)
  const int hh = wv & 1;             // PV: h-half (128 h)

  const size_t base = (size_t)nb * T_ * H_;
  const u16* qp = q + base;          // pre-scaled by SCALE_L2E
  const u16* kp = k + base;
  const u16* vtp = vT + ((size_t)n * H_ * B_ + b) * T_;

  __shared__ __align__(16) u16 Ks[2][64][256];   // 64 KB, 5-bit XOR swizzle
  __shared__ __align__(16) u16 Vs[2][64][256];   // 64 KB, packed-4h + 3-bit XOR
  __shared__ __align__(16) u16 Ps[4][32][72];    // 18,432 B (cols 64..67: l-sums)

  const int qrow0 = qt * 128 + qh * 32;
  bf16x8 qf[16];
  #pragma unroll
  for (int kc = 0; kc < 16; kc++)
    qf[kc] = *reinterpret_cast<const bf16x8*>(
        qp + (size_t)(qrow0 + l32) * H_ + kc * 16 + hi * 8);

  f32x16 o[4];
  #pragma unroll
  for (int ot = 0; ot < 4; ot++)
    #pragma unroll
    for (int r = 0; r < 16; r++) o[ot][r] = 0.f;
  float lper[16];
  #pragma unroll
  for (int r = 0; r < 16; r++) lper[r] = 0.f;

  // K staging: 32 DMA instrs (4/wave), each fills 2 rows (512B each).
  // Lane l -> row 2*idx+(l>>5), 16B slot (l&31). Slot s of row r holds
  // K[r][(s ^ (r&31))*8 ..], so source col = ((l&31) ^ (row&31))*8.
  auto stage_k = [&](int ktN, int buf) {
    #pragma unroll
    for (int i = 0; i < 4; i++) {
      int idx = wv * 4 + i;
      int row = 2 * idx + hi;
      const u16* src = kp + (size_t)(ktN * 64 + row) * H_ +
                       ((l32 ^ (row & 31)) * 8);
      gload_lds16(src, &Ks[buf][2 * idx][0]);
    }
  };
  // V staging: 32 DMA instrs (4/wave), each fills 2 physical rows.
  // Physical row p holds h = p*4..p*4+3 (64 keys each). Slot s of row p
  // holds unswizzled block u = s ^ (p&7); u -> h = p*4 + (u>>3),
  // key0 = (u&7)*8.  Lane l: p = 2*idx+(l>>5), s = l&31.
  auto stage_v = [&](int ktN, int buf) {
    #pragma unroll
    for (int i = 0; i < 4; i++) {
      int idx = wv * 4 + i;
      int p = 2 * idx + hi;
      int u = l32 ^ (p & 7);
      const u16* src = vtp + (size_t)(p * 4 + (u >> 3)) * BT_ +
                       ktN * 64 + (u & 7) * 8;
      gload_lds16(src, &Vs[buf][2 * idx][0]);
    }
  };

  // Prologue: stage tiles 0 and 1; wait only tile 0 (own 8 newest = tile 1).
  stage_k(0, 0); stage_v(0, 0);
  stage_k(1, 1); stage_v(1, 1);
  asm volatile("s_waitcnt vmcnt(8)" ::: "memory");
  __builtin_amdgcn_s_barrier();
  __builtin_amdgcn_sched_barrier(0);

  const int krow = kh * 32 + l32;

  #pragma unroll 1
  for (int kt = 0; kt < 16; kt++) {
    const int c = kt & 1;

    // ---- QK phase: reads Ks[c] (tile kt; landed: vmcnt+barrier last iter)
    f32x16 sa, sb;
    #pragma unroll
    for (int r = 0; r < 16; r++) { sa[r] = 0.f; sb[r] = 0.f; }
    __builtin_amdgcn_s_setprio(1);
    #pragma unroll
    for (int kc = 0; kc < 16; kc += 2) {
      // fragment blocks kc*2+hi and (kc+1)*2+hi, swizzled by ^l32 (krow&31)
      bf16x8 kfa = *reinterpret_cast<const bf16x8*>(
          &Ks[c][krow][(((kc * 2 + hi) ^ l32) * 8)]);
      bf16x8 kfb = *reinterpret_cast<const bf16x8*>(
          &Ks[c][krow][(((kc * 2 + 2 + hi) ^ l32) * 8)]);
      sa = mfma32(qf[kc], kfa, sa);
      sb = mfma32(qf[kc + 1], kfb, sb);
    }
    __builtin_amdgcn_s_setprio(0);

    #pragma unroll
    for (int r = 0; r < 16; r++) {
      float p = exp2f(sa[r] + sb[r]);   // log2e pre-folded into q
      lper[r] += p;
      Ps[qh][(r & 3) + 8 * (r >> 2) + 4 * hi][kh * 32 + l32] = f2bf(p);
    }

    // ---- B1: Ps writes visible; Ks[c] readers (all waves) retired.
    asm volatile("s_waitcnt lgkmcnt(0)" ::: "memory");
    __builtin_amdgcn_s_barrier();
    __builtin_amdgcn_sched_barrier(0);

    // K-stage(kt+2 -> c): safe (Ks[c] last read before B1). Drains ~2 iters
    // from now; never force-drained by a barrier.
    if (kt < 14) stage_k(kt + 2, c);

    // ---- PV phase: reads Ps + Vs[c]
    bf16x8 pa[4];
    #pragma unroll
    for (int kc2 = 0; kc2 < 4; kc2++)
      pa[kc2] = *reinterpret_cast<const bf16x8*>(
          &Ps[qh][l32][kc2 * 16 + hi * 8]);
    __builtin_amdgcn_s_setprio(1);
    #pragma unroll
    for (int ot = 0; ot < 4; ot++) {
      const int p = hh * 32 + ot * 8 + (l32 >> 2);
      #pragma unroll
      for (int kc2 = 0; kc2 < 4; kc2++) {
        int s = ((l32 & 3) * 8 + kc2 * 2 + hi) ^ (l32 >> 2);
        bf16x8 vf = *reinterpret_cast<const bf16x8*>(&Vs[c][p][s * 8]);
        o[ot] = mfma32(pa[kc2], vf, o[ot]);
      }
    }
    __builtin_amdgcn_s_setprio(0);

    // ---- B2: own K/V(kt+1) landed (allow only K(kt+2)'s 4 loads in flight);
    // barrier -> ALL waves' tile-(kt+1) slices landed.  Vs[c]/Ps readers
    // retired here.  Tail iters drain fully (no further stages to count).
    if (kt < 14) {
      asm volatile("s_waitcnt vmcnt(4)" ::: "memory");
    } else {
      asm volatile("s_waitcnt vmcnt(0)" ::: "memory");
    }
    __builtin_amdgcn_s_barrier();
    __builtin_amdgcn_sched_barrier(0);

    // V-stage(kt+2 -> c): safe (Vs[c] last read before B2).
    if (kt < 14) stage_v(kt + 2, c);
  }

  #pragma unroll
  for (int r = 0; r < 16; r++) {
    #pragma unroll
    for (int off = 1; off < 32; off <<= 1)
      lper[r] += __shfl_xor(lper[r], off, 64);
  }
  if (l32 == 0) {
    #pragma unroll
    for (int r = 0; r < 16; r++) {
      int row = (r & 3) + 8 * (r >> 2) + 4 * hi;
      *reinterpret_cast<float*>(&Ps[qh][row][64 + 2 * kh]) = lper[r];
    }
  }
  __syncthreads();

  float invl[16];
  #pragma unroll
  for (int r = 0; r < 16; r++) {
    int row = (r & 3) + 8 * (r >> 2) + 4 * hi;
    float l0 = *reinterpret_cast<const float*>(&Ps[qh][row][64]);
    float l1 = *reinterpret_cast<const float*>(&Ps[qh][row][66]);
    invl[r] = 1.0f / (l0 + l1);
  }

  u16* Ew = reinterpret_cast<u16*>(&Ks[0][0][0]) + wv * 1280;   // 8x1280 u16
  const int grow = b * 1024 + qrow0 + l32;
  #pragma unroll
  for (int ot = 0; ot < 4; ot++) {
    #pragma unroll
    for (int r = 0; r < 16; r++) {
      int row = (r & 3) + 8 * (r >> 2) + 4 * hi;
      Ew[row * 40 + l32] = f2bf(o[ot][r] * invl[r]);
    }
    int ht = hh * 4 + ot;
    uint4 v0 = *reinterpret_cast<const uint4*>(&Ew[l32 * 40 + hi * 16]);
    uint4 v1 = *reinterpret_cast<const uint4*>(&Ew[l32 * 40 + hi * 16 + 8]);
    u16* op = obuf + (((size_t)n * 8 + ht) * BT_ + grow) * 32 + hi * 16;
    *reinterpret_cast<uint4*>(op) = v0;
    *reinterpret_cast<uint4*>(op + 8) = v1;
  }
}

// ---------- K4: combine 8 branches (signed) + LayerNorm over H ----------
__global__ __launch_bounds__(256) void combine_ln2_kernel(
    const u16* __restrict__ obuf, const float* __restrict__ w,
    const float* __restrict__ bi, float* __restrict__ out) {
  const int row = blockIdx.x;
  const int h = threadIdx.x;
  float o[8];
  #pragma unroll
  for (int nn = 0; nn < 8; nn++)
    o[nn] = bf1(obuf[(((size_t)nn * 8 + (h >> 5)) * BT_ + row) * 32 + (h & 31)]);
  float re = o[0] - o[1] - o[2] - o[3];
  float im = o[4] + o[5] + o[6] - o[7];
  float sr = re, si = im, sr2 = re * re, si2 = im * im;
  block_reduce4(sr, si, sr2, si2);
  const float inv = 1.0f / H_;
  float mr = sr * inv, mi = si * inv;
  float vr = sr2 * inv - mr * mr, vi = si2 * inv - mi * mi;
  float rr = rsqrtf(vr + EPS), ri = rsqrtf(vi + EPS);
  float ww = w[h], bb = bi[h];
  float2 res;
  res.x = (re - mr) * rr * ww + bb;
  res.y = (im - mi) * ri * ww + bb;
  reinterpret_cast<float2*>(out)[(size_t)row * H_ + h] = res;
}

extern "C" void kernel_launch(void* const* d_in, const int* in_sizes, int n_in,
                              void* d_out, int out_size, void* d_ws, size_t ws_size,
                              hipStream_t stream) {
  const float* x    = (const float*)d_in[0];
  const float* Wq   = (const float*)d_in[1];
  const float* bq   = (const float*)d_in[2];
  const float* Wk   = (const float*)d_in[3];
  const float* bk   = (const float*)d_in[4];
  const float* Wv   = (const float*)d_in[5];
  const float* bv   = (const float*)d_in[6];
  const float* ln1w = (const float*)d_in[7];
  const float* ln1b = (const float*)d_in[8];
  const float* ln2w = (const float*)d_in[9];
  const float* ln2b = (const float*)d_in[10];

  // Workspace (128 MB), lifetime-aliased:
  //  [0,8)  xn  (dead after qkv)  |  [0,32)  obuf (written by attn, after qkv)
  //  [8,11) wT  (dead after qkv)
  //  [32,64) vT ; [64,96) q ; [96,128) k
  char* ws = (char*)d_ws;
  u16* xnr  = (u16*)(ws);
  u16* xni  = (u16*)(ws + (4ull  << 20));
  u16* wTb  = (u16*)(ws + (8ull  << 20));
  u16* obuf = (u16*)(ws);
  u16* vT   = (u16*)(ws + (32ull << 20));
  u16* qbuf = (u16*)(ws + (64ull << 20));
  u16* kbuf = (u16*)(ws + (96ull << 20));

  ln1_kernel<<<BT_, 256, 0, stream>>>(x, ln1w, ln1b, xnr, xni);
  wprep_kernel<<<dim3(4, 4, 24), 256, 0, stream>>>(Wq, Wk, Wv, wTb);
  qkv_kernel<<<dim3(64, 24), 256, 0, stream>>>(xnr, xni, wTb, bq, bk, bv,
                                               qbuf, kbuf, vT);
  attn_kernel<<<dim3(512), 512, 0, stream>>>(qbuf, kbuf, vT, obuf);
  combine_ln2_kernel<<<BT_, 256, 0, stream>>>(obuf, ln2w, ln2b, (float*)d_out);
}

// Round 12
// 170.315 us; speedup vs baseline: 2.2926x; 1.0339x over previous
//
#include <hip/hip_runtime.h>
#include <math.h>

#define B_ 8
#define T_ 1024
#define F_ 256
#define H_ 256
#define BT_ (B_*T_)          // 8192
constexpr float EPS = 1e-5f;
// 1/sqrt(256) * log2(e), folded into qbuf: softmax uses raw v_exp_f32 (exp2).
constexpr float SCALE_L2E = 0.09016844005555963f;

typedef unsigned int u32;
typedef unsigned short u16;
typedef __attribute__((ext_vector_type(8))) short bf16x8;    // 8 bf16 = 4 VGPRs
typedef __attribute__((ext_vector_type(4))) float f32x4;
typedef __attribute__((ext_vector_type(16))) float f32x16;

// ---------- bf16 helpers ----------
__device__ __forceinline__ float bf1(u16 p) { return __uint_as_float(((u32)p) << 16); }
__device__ __forceinline__ u16 f2bf(float f) {
  u32 u = __float_as_uint(f);
  u32 r = u + 0x7FFFu + ((u >> 16) & 1u);   // RNE
  return (u16)(r >> 16);
}

__device__ __forceinline__ f32x4 mfma16(bf16x8 a, bf16x8 b, f32x4 c) {
  return __builtin_amdgcn_mfma_f32_16x16x32_bf16(a, b, c, 0, 0, 0);
}
__device__ __forceinline__ f32x16 mfma32(bf16x8 a, bf16x8 b, f32x16 c) {
  return __builtin_amdgcn_mfma_f32_32x32x16_bf16(a, b, c, 0, 0, 0);
}

// async global->LDS, 16B per lane; dest = wave-uniform base + lane*16
__device__ __forceinline__ void gload_lds16(const u16* g, u16* l) {
  __builtin_amdgcn_global_load_lds(
      (const __attribute__((address_space(1))) u32*)(uintptr_t)g,
      (__attribute__((address_space(3))) u32*)(u32)(uintptr_t)l,
      16, 0, 0);
}

// ---------- block-wide reduction of 4 values over 256 threads ----------
__device__ __forceinline__ void block_reduce4(float& a, float& b, float& c, float& d) {
  #pragma unroll
  for (int off = 32; off > 0; off >>= 1) {
    a += __shfl_down(a, off, 64);
    b += __shfl_down(b, off, 64);
    c += __shfl_down(c, off, 64);
    d += __shfl_down(d, off, 64);
  }
  __shared__ float red[4][4];
  int wid = threadIdx.x >> 6;
  int lane = threadIdx.x & 63;
  if (lane == 0) { red[0][wid] = a; red[1][wid] = b; red[2][wid] = c; red[3][wid] = d; }
  __syncthreads();
  a = red[0][0] + red[0][1] + red[0][2] + red[0][3];
  b = red[1][0] + red[1][1] + red[1][2] + red[1][3];
  c = red[2][0] + red[2][1] + red[2][2] + red[2][3];
  d = red[3][0] + red[3][1] + red[3][2] + red[3][3];
}

// ---------- K1: LayerNorm over F per (b,t,plane); emit bf16 real/imag ----------
__global__ __launch_bounds__(256) void ln1_kernel(
    const float* __restrict__ x, const float* __restrict__ w, const float* __restrict__ bi,
    u16* __restrict__ xnr, u16* __restrict__ xni) {
  const int row = blockIdx.x;
  const int f = threadIdx.x;
  float2 xv = reinterpret_cast<const float2*>(x)[row * F_ + f];
  float sr = xv.x, si = xv.y, sr2 = xv.x * xv.x, si2 = xv.y * xv.y;
  block_reduce4(sr, si, sr2, si2);
  const float inv = 1.0f / F_;
  float mr = sr * inv, mi = si * inv;
  float vr = sr2 * inv - mr * mr, vi = si2 * inv - mi * mi;
  float rr = rsqrtf(vr + EPS), ri = rsqrtf(vi + EPS);
  float ww = w[f], bb = bi[f];
  xnr[row * F_ + f] = f2bf((xv.x - mr) * rr * ww + bb);
  xni[row * F_ + f] = f2bf((xv.y - mi) * ri * ww + bb);
}

// ---------- K2a: weight prep — transpose+convert W[z][f][h] (f32) -> wT[z][h][f] (bf16) ----------
__global__ __launch_bounds__(256) void wprep_kernel(
    const float* __restrict__ Wq, const float* __restrict__ Wk, const float* __restrict__ Wv,
    u16* __restrict__ wT) {
  const int z = blockIdx.z;
  const int m = z >> 3, n = z & 7;
  const float* W = (m == 0 ? Wq : (m == 1 ? Wk : Wv)) + (size_t)n * F_ * H_;
  const int ft = blockIdx.x * 64;
  const int ht = blockIdx.y * 64;
  __shared__ __align__(16) u16 Ts[64][72];

  const int tid = threadIdx.x;
  #pragma unroll
  for (int i = 0; i < 4; i++) {
    int id = tid + i * 256;
    int r = id >> 4, c4 = (id & 15) * 4;
    float4 p = *reinterpret_cast<const float4*>(&W[(size_t)(ft + r) * H_ + ht + c4]);
    Ts[r][c4 + 0] = f2bf(p.x); Ts[r][c4 + 1] = f2bf(p.y);
    Ts[r][c4 + 2] = f2bf(p.z); Ts[r][c4 + 3] = f2bf(p.w);
  }
  __syncthreads();
  u16* op = wT + (size_t)z * F_ * H_ + (size_t)ht * F_ + ft;
  #pragma unroll
  for (int i = 0; i < 2; i++) {
    int id = tid + i * 256;
    int hl = id & 63, g = id >> 6;
    u16 tmp[8];
    #pragma unroll
    for (int j = 0; j < 8; j++) tmp[j] = Ts[g * 8 + j][hl];
    *reinterpret_cast<uint4*>(op + (size_t)hl * F_ + g * 8) =
        *reinterpret_cast<const uint4*>(tmp);
  }
}

// ---------- K2b: QKV projections — bf16 MFMA GEMM, 128x256 tile (full H), BK=64 ----------
__global__ __launch_bounds__(256, 2) void qkv_kernel(
    const u16* __restrict__ xnr, const u16* __restrict__ xni, const u16* __restrict__ wT,
    const float* __restrict__ bq, const float* __restrict__ bk, const float* __restrict__ bv,
    u16* __restrict__ qo, u16* __restrict__ ko, u16* __restrict__ vTo) {
  const int z = blockIdx.y;
  const int m = z >> 3, n = z & 7;
  int sel; const float* bias; u16* out;
  if (m == 0)      { sel = (n >> 1) & 1;  bias = bq; out = qo + (size_t)n * BT_ * H_; }
  else if (m == 1) { sel = n & 1;         bias = bk; out = ko + (size_t)n * BT_ * H_; }
  else             { sel = __popc(n) & 1; bias = bv; out = nullptr; }
  const float osc = (m == 0) ? SCALE_L2E : 1.0f;   // q pre-scaled by 1/16*log2(e)
  const u16* A = sel ? xni : xnr;
  const u16* wp = wT + (size_t)z * F_ * H_;
  bias += n * H_;
  const int rowbase = blockIdx.x * 128;

  __shared__ __align__(16) u16 As[2][128 * 32];   // 16 KB
  __shared__ __align__(16) u16 Bs[2][256 * 32];   // 32 KB
  __shared__ __align__(16) u16 Epi[4][1536];      // q/k: [16][72]; v: [64][24]

  const int tid = threadIdx.x;
  const int wv = tid >> 6, lane = tid & 63;
  const int quad = lane >> 4, l16 = lane & 15;
  const int wrow = wv >> 1, wcol = wv & 1;        // wave: 64 rows x 128 cols

  f32x4 acc[4][8];
  #pragma unroll
  for (int i = 0; i < 4; i++)
    #pragma unroll
    for (int j = 0; j < 8; j++) acc[i][j] = (f32x4){0.f, 0.f, 0.f, 0.f};

  const int ar = tid >> 2;            // A staging: row tid>>2, k-chunk (tid&3)*8
  const int ak = (tid & 3) * 8;

  #pragma unroll 1
  for (int kb = 0; kb < F_; kb += 64) {
    #pragma unroll
    for (int h = 0; h < 2; h++) {
      // A half: 128x32 = 8KB = 2 DMA groups
      gload_lds16(A + (size_t)(rowbase + ar) * F_ + kb + h * 32 + ak,
                  &As[h][tid * 8]);
      gload_lds16(A + (size_t)(rowbase + 64 + ar) * F_ + kb + h * 32 + ak,
                  &As[h][2048 + tid * 8]);
      // B half: 256x32 = 16KB = 4 DMA groups
      #pragma unroll
      for (int c = 0; c < 4; c++)
        gload_lds16(wp + (size_t)(c * 64 + ar) * F_ + kb + h * 32 + ak,
                    &Bs[h][c * 2048 + tid * 8]);
    }
    __syncthreads();
    #pragma unroll
    for (int h = 0; h < 2; h++) {
      bf16x8 a[4], b[8];
      #pragma unroll
      for (int mi = 0; mi < 4; mi++)
        a[mi] = *reinterpret_cast<const bf16x8*>(
            &As[h][(wrow * 64 + mi * 16 + l16) * 32 + quad * 8]);
      #pragma unroll
      for (int nj = 0; nj < 8; nj++)
        b[nj] = *reinterpret_cast<const bf16x8*>(
            &Bs[h][(wcol * 128 + nj * 16 + l16) * 32 + quad * 8]);
      #pragma unroll
      for (int mi = 0; mi < 4; mi++)
        #pragma unroll
        for (int nj = 0; nj < 8; nj++)
          acc[mi][nj] = mfma16(a[mi], b[nj], acc[mi][nj]);
    }
    __syncthreads();
  }

  float bias8[8];
  #pragma unroll
  for (int nj = 0; nj < 8; nj++)
    bias8[nj] = bias[wcol * 128 + nj * 16 + l16];

  if (m != 2) {   // q/k: row-major store, two 64-col passes
    #pragma unroll
    for (int pass = 0; pass < 2; pass++) {
      #pragma unroll
      for (int mi = 0; mi < 4; mi++) {
        #pragma unroll
        for (int nj4 = 0; nj4 < 4; nj4++) {
          int nj = pass * 4 + nj4;
          #pragma unroll
          for (int r = 0; r < 4; r++)
            Epi[wv][(quad * 4 + r) * 72 + nj4 * 16 + l16] =
                f2bf((acc[mi][nj][r] + bias8[nj]) * osc);
        }
        int row = rowbase + wrow * 64 + mi * 16 + l16;
        uint4 v0 = *reinterpret_cast<const uint4*>(&Epi[wv][l16 * 72 + quad * 16]);
        uint4 v1 = *reinterpret_cast<const uint4*>(&Epi[wv][l16 * 72 + quad * 16 + 8]);
        u16* op = out + (size_t)row * H_ + wcol * 128 + pass * 64 + quad * 16;
        *reinterpret_cast<uint4*>(op) = v0;
        *reinterpret_cast<uint4*>(op + 8) = v1;
      }
    }
  } else {        // v: transposed store into vT[n][h][bt], two 64-h passes
    #pragma unroll
    for (int pass = 0; pass < 2; pass++) {
      #pragma unroll
      for (int mi = 0; mi < 4; mi++) {
        #pragma unroll
        for (int nj4 = 0; nj4 < 4; nj4++) {
          int nj = pass * 4 + nj4;
          #pragma unroll
          for (int r = 0; r < 4; r++)
            Epi[wv][(nj4 * 16 + l16) * 24 + quad * 4 + r] =
                f2bf(acc[mi][nj][r] + bias8[nj]);
        }
        int hloc = lane;                  // 0..63
        uint4 w0 = *reinterpret_cast<const uint4*>(&Epi[wv][hloc * 24]);
        uint4 w1 = *reinterpret_cast<const uint4*>(&Epi[wv][hloc * 24 + 8]);
        u16* op = vTo + (size_t)n * H_ * BT_ +
                  (size_t)(wcol * 128 + pass * 64 + hloc) * BT_ +
                  rowbase + wrow * 64 + mi * 16;
        *reinterpret_cast<uint4*>(op) = w0;
        *reinterpret_cast<uint4*>(op + 8) = w1;
      }
    }
  }
}

// ---------- K3: MFMA flash attention ----------
// R21 == R14 structure, exp2 fold done RIGHT: __builtin_amdgcn_exp2f
// (raw v_exp_f32, 1 instr). R20's exp2f() was the correct-rounding ocml
// version with denorm fixup (~5 VALU ops/call) -> VALUBusy 26.5->30.9,
// 103.4 -> 110.4 us regression. log2e stays folded into q pre-scale.
// Schedule (counted vmcnt, split K/V prefetch, distance ~1 iter each):
//   QK(kt) | softmax | B1(lgkm0) | stage_k(kt+2,c) | PV(kt) |
//   B2(vmcnt 4/0) | stage_v(kt+2,c)
// Swizzles: K 5-bit XOR (read block (kc*2+hi)^l32 -> 32 distinct slots);
// V packed-4h [64][256] 3-bit XOR (slot ((l32&3)*8+kc2*2+hi)^(l32>>2)).
__global__ __launch_bounds__(512, 2) void attn_kernel(
    const u16* __restrict__ q, const u16* __restrict__ k, const u16* __restrict__ vT,
    u16* __restrict__ obuf) {
  const int fid = blockIdx.x;        // 0..511
  const int qt = fid >> 6;           // 0..7 : 128 query rows
  const int nb = fid & 63;           // n*8 + b ; XCD = nb & 7
  const int n = nb >> 3, b = nb & 7;
  const int tid = threadIdx.x;
  const int wv = tid >> 6, lane = tid & 63;
  const int hi = lane >> 5, l32 = lane & 31;
  const int qh = wv >> 1;            // q 32-row group (0..3)
  const int kh = wv & 1;             // QK: key-half (32 keys)
  const int hh = wv & 1;             // PV: h-half (128 h)

  const size_t base = (size_t)nb * T_ * H_;
  const u16* qp = q + base;          // pre-scaled by SCALE_L2E
  const u16* kp = k + base;
  const u16* vtp = vT + ((size_t)n * H_ * B_ + b) * T_;

  __shared__ __align__(16) u16 Ks[2][64][256];   // 64 KB, 5-bit XOR swizzle
  __shared__ __align__(16) u16 Vs[2][64][256];   // 64 KB, packed-4h + 3-bit XOR
  __shared__ __align__(16) u16 Ps[4][32][72];    // 18,432 B (cols 64..67: l-sums)

  const int qrow0 = qt * 128 + qh * 32;
  bf16x8 qf[16];
  #pragma unroll
  for (int kc = 0; kc < 16; kc++)
    qf[kc] = *reinterpret_cast<const bf16x8*>(
        qp + (size_t)(qrow0 + l32) * H_ + kc * 16 + hi * 8);

  f32x16 o[4];
  #pragma unroll
  for (int ot = 0; ot < 4; ot++)
    #pragma unroll
    for (int r = 0; r < 16; r++) o[ot][r] = 0.f;
  float lper[16];
  #pragma unroll
  for (int r = 0; r < 16; r++) lper[r] = 0.f;

  // K staging: 32 DMA instrs (4/wave), each fills 2 rows (512B each).
  // Lane l -> row 2*idx+(l>>5), 16B slot (l&31). Slot s of row r holds
  // K[r][(s ^ (r&31))*8 ..], so source col = ((l&31) ^ (row&31))*8.
  auto stage_k = [&](int ktN, int buf) {
    #pragma unroll
    for (int i = 0; i < 4; i++) {
      int idx = wv * 4 + i;
      int row = 2 * idx + hi;
      const u16* src = kp + (size_t)(ktN * 64 + row) * H_ +
                       ((l32 ^ (row & 31)) * 8);
      gload_lds16(src, &Ks[buf][2 * idx][0]);
    }
  };
  // V staging: 32 DMA instrs (4/wave), each fills 2 physical rows.
  // Physical row p holds h = p*4..p*4+3 (64 keys each). Slot s of row p
  // holds unswizzled block u = s ^ (p&7); u -> h = p*4 + (u>>3),
  // key0 = (u&7)*8.  Lane l: p = 2*idx+(l>>5), s = l&31.
  auto stage_v = [&](int ktN, int buf) {
    #pragma unroll
    for (int i = 0; i < 4; i++) {
      int idx = wv * 4 + i;
      int p = 2 * idx + hi;
      int u = l32 ^ (p & 7);
      const u16* src = vtp + (size_t)(p * 4 + (u >> 3)) * BT_ +
                       ktN * 64 + (u & 7) * 8;
      gload_lds16(src, &Vs[buf][2 * idx][0]);
    }
  };

  // Prologue: stage tiles 0 and 1; wait only tile 0 (own 8 newest = tile 1).
  stage_k(0, 0); stage_v(0, 0);
  stage_k(1, 1); stage_v(1, 1);
  asm volatile("s_waitcnt vmcnt(8)" ::: "memory");
  __builtin_amdgcn_s_barrier();
  __builtin_amdgcn_sched_barrier(0);

  const int krow = kh * 32 + l32;

  #pragma unroll 1
  for (int kt = 0; kt < 16; kt++) {
    const int c = kt & 1;

    // ---- QK phase: reads Ks[c] (tile kt; landed: vmcnt+barrier last iter)
    f32x16 sa, sb;
    #pragma unroll
    for (int r = 0; r < 16; r++) { sa[r] = 0.f; sb[r] = 0.f; }
    __builtin_amdgcn_s_setprio(1);
    #pragma unroll
    for (int kc = 0; kc < 16; kc += 2) {
      // fragment blocks kc*2+hi and (kc+1)*2+hi, swizzled by ^l32 (krow&31)
      bf16x8 kfa = *reinterpret_cast<const bf16x8*>(
          &Ks[c][krow][(((kc * 2 + hi) ^ l32) * 8)]);
      bf16x8 kfb = *reinterpret_cast<const bf16x8*>(
          &Ks[c][krow][(((kc * 2 + 2 + hi) ^ l32) * 8)]);
      sa = mfma32(qf[kc], kfa, sa);
      sb = mfma32(qf[kc + 1], kfb, sb);
    }
    __builtin_amdgcn_s_setprio(0);

    #pragma unroll
    for (int r = 0; r < 16; r++) {
      float p = __builtin_amdgcn_exp2f(sa[r] + sb[r]);  // log2e pre-folded
      lper[r] += p;
      Ps[qh][(r & 3) + 8 * (r >> 2) + 4 * hi][kh * 32 + l32] = f2bf(p);
    }

    // ---- B1: Ps writes visible; Ks[c] readers (all waves) retired.
    asm volatile("s_waitcnt lgkmcnt(0)" ::: "memory");
    __builtin_amdgcn_s_barrier();
    __builtin_amdgcn_sched_barrier(0);

    // K-stage(kt+2 -> c): safe (Ks[c] last read before B1). Drains ~2 iters
    // from now; never force-drained by a barrier.
    if (kt < 14) stage_k(kt + 2, c);

    // ---- PV phase: reads Ps + Vs[c]
    bf16x8 pa[4];
    #pragma unroll
    for (int kc2 = 0; kc2 < 4; kc2++)
      pa[kc2] = *reinterpret_cast<const bf16x8*>(
          &Ps[qh][l32][kc2 * 16 + hi * 8]);
    __builtin_amdgcn_s_setprio(1);
    #pragma unroll
    for (int ot = 0; ot < 4; ot++) {
      const int p = hh * 32 + ot * 8 + (l32 >> 2);
      #pragma unroll
      for (int kc2 = 0; kc2 < 4; kc2++) {
        int s = ((l32 & 3) * 8 + kc2 * 2 + hi) ^ (l32 >> 2);
        bf16x8 vf = *reinterpret_cast<const bf16x8*>(&Vs[c][p][s * 8]);
        o[ot] = mfma32(pa[kc2], vf, o[ot]);
      }
    }
    __builtin_amdgcn_s_setprio(0);

    // ---- B2: own K/V(kt+1) landed (allow only K(kt+2)'s 4 loads in flight);
    // barrier -> ALL waves' tile-(kt+1) slices landed.  Vs[c]/Ps readers
    // retired here.  Tail iters drain fully (no further stages to count).
    if (kt < 14) {
      asm volatile("s_waitcnt vmcnt(4)" ::: "memory");
    } else {
      asm volatile("s_waitcnt vmcnt(0)" ::: "memory");
    }
    __builtin_amdgcn_s_barrier();
    __builtin_amdgcn_sched_barrier(0);

    // V-stage(kt+2 -> c): safe (Vs[c] last read before B2).
    if (kt < 14) stage_v(kt + 2, c);
  }

  #pragma unroll
  for (int r = 0; r < 16; r++) {
    #pragma unroll
    for (int off = 1; off < 32; off <<= 1)
      lper[r] += __shfl_xor(lper[r], off, 64);
  }
  if (l32 == 0) {
    #pragma unroll
    for (int r = 0; r < 16; r++) {
      int row = (r & 3) + 8 * (r >> 2) + 4 * hi;
      *reinterpret_cast<float*>(&Ps[qh][row][64 + 2 * kh]) = lper[r];
    }
  }
  __syncthreads();

  float invl[16];
  #pragma unroll
  for (int r = 0; r < 16; r++) {
    int row = (r & 3) + 8 * (r >> 2) + 4 * hi;
    float l0 = *reinterpret_cast<const float*>(&Ps[qh][row][64]);
    float l1 = *reinterpret_cast<const float*>(&Ps[qh][row][66]);
    invl[r] = 1.0f / (l0 + l1);
  }

  u16* Ew = reinterpret_cast<u16*>(&Ks[0][0][0]) + wv * 1280;   // 8x1280 u16
  const int grow = b * 1024 + qrow0 + l32;
  #pragma unroll
  for (int ot = 0; ot < 4; ot++) {
    #pragma unroll
    for (int r = 0; r < 16; r++) {
      int row = (r & 3) + 8 * (r >> 2) + 4 * hi;
      Ew[row * 40 + l32] = f2bf(o[ot][r] * invl[r]);
    }
    int ht = hh * 4 + ot;
    uint4 v0 = *reinterpret_cast<const uint4*>(&Ew[l32 * 40 + hi * 16]);
    uint4 v1 = *reinterpret_cast<const uint4*>(&Ew[l32 * 40 + hi * 16 + 8]);
    u16* op = obuf + (((size_t)n * 8 + ht) * BT_ + grow) * 32 + hi * 16;
    *reinterpret_cast<uint4*>(op) = v0;
    *reinterpret_cast<uint4*>(op + 8) = v1;
  }
}

// ---------- K4: combine 8 branches (signed) + LayerNorm over H ----------
__global__ __launch_bounds__(256) void combine_ln2_kernel(
    const u16* __restrict__ obuf, const float* __restrict__ w,
    const float* __restrict__ bi, float* __restrict__ out) {
  const int row = blockIdx.x;
  const int h = threadIdx.x;
  float o[8];
  #pragma unroll
  for (int nn = 0; nn < 8; nn++)
    o[nn] = bf1(obuf[(((size_t)nn * 8 + (h >> 5)) * BT_ + row) * 32 + (h & 31)]);
  float re = o[0] - o[1] - o[2] - o[3];
  float im = o[4] + o[5] + o[6] - o[7];
  float sr = re, si = im, sr2 = re * re, si2 = im * im;
  block_reduce4(sr, si, sr2, si2);
  const float inv = 1.0f / H_;
  float mr = sr * inv, mi = si * inv;
  float vr = sr2 * inv - mr * mr, vi = si2 * inv - mi * mi;
  float rr = rsqrtf(vr + EPS), ri = rsqrtf(vi + EPS);
  float ww = w[h], bb = bi[h];
  float2 res;
  res.x = (re - mr) * rr * ww + bb;
  res.y = (im - mi) * ri * ww + bb;
  reinterpret_cast<float2*>(out)[(size_t)row * H_ + h] = res;
}

extern "C" void kernel_launch(void* const* d_in, const int* in_sizes, int n_in,
                              void* d_out, int out_size, void* d_ws, size_t ws_size,
                              hipStream_t stream) {
  const float* x    = (const float*)d_in[0];
  const float* Wq   = (const float*)d_in[1];
  const float* bq   = (const float*)d_in[2];
  const float* Wk   = (const float*)d_in[3];
  const float* bk   = (const float*)d_in[4];
  const float* Wv   = (const float*)d_in[5];
  const float* bv   = (const float*)d_in[6];
  const float* ln1w = (const float*)d_in[7];
  const float* ln1b = (const float*)d_in[8];
  const float* ln2w = (const float*)d_in[9];
  const float* ln2b = (const float*)d_in[10];

  // Workspace (128 MB), lifetime-aliased:
  //  [0,8)  xn  (dead after qkv)  |  [0,32)  obuf (written by attn, after qkv)
  //  [8,11) wT  (dead after qkv)
  //  [32,64) vT ; [64,96) q ; [96,128) k
  char* ws = (char*)d_ws;
  u16* xnr  = (u16*)(ws);
  u16* xni  = (u16*)(ws + (4ull  << 20));
  u16* wTb  = (u16*)(ws + (8ull  << 20));
  u16* obuf = (u16*)(ws);
  u16* vT   = (u16*)(ws + (32ull << 20));
  u16* qbuf = (u16*)(ws + (64ull << 20));
  u16* kbuf = (u16*)(ws + (96ull << 20));

  ln1_kernel<<<BT_, 256, 0, stream>>>(x, ln1w, ln1b, xnr, xni);
  wprep_kernel<<<dim3(4, 4, 24), 256, 0, stream>>>(Wq, Wk, Wv, wTb);
  qkv_kernel<<<dim3(64, 24), 256, 0, stream>>>(xnr, xni, wTb, bq, bk, bv,
                                               qbuf, kbuf, vT);
  attn_kernel<<<dim3(512), 512, 0, stream>>>(qbuf, kbuf, vT, obuf);
  combine_ln2_kernel<<<BT_, 256, 0, stream>>>(obuf, ln2w, ln2b, (float*)d_out);
}

// Round 13
// 166.968 us; speedup vs baseline: 2.3385x; 1.0200x over previous
//
#include <hip/hip_runtime.h>
#include <math.h>

#define B_ 8
#define T_ 1024
#define F_ 256
#define H_ 256
#define BT_ (B_*T_)          // 8192
constexpr float EPS = 1e-5f;
// 1/sqrt(256) * log2(e), folded into qbuf: softmax uses raw v_exp_f32 (exp2).
constexpr float SCALE_L2E = 0.09016844005555963f;

typedef unsigned int u32;
typedef unsigned short u16;
typedef __attribute__((ext_vector_type(8))) short bf16x8;    // 8 bf16 = 4 VGPRs
typedef __attribute__((ext_vector_type(4))) float f32x4;
typedef __attribute__((ext_vector_type(16))) float f32x16;

// ---------- bf16 helpers ----------
__device__ __forceinline__ float bf1(u16 p) { return __uint_as_float(((u32)p) << 16); }
__device__ __forceinline__ u16 f2bf(float f) {
  u32 u = __float_as_uint(f);
  u32 r = u + 0x7FFFu + ((u >> 16) & 1u);   // RNE
  return (u16)(r >> 16);
}

__device__ __forceinline__ f32x4 mfma16(bf16x8 a, bf16x8 b, f32x4 c) {
  return __builtin_amdgcn_mfma_f32_16x16x32_bf16(a, b, c, 0, 0, 0);
}
__device__ __forceinline__ f32x16 mfma32(bf16x8 a, bf16x8 b, f32x16 c) {
  return __builtin_amdgcn_mfma_f32_32x32x16_bf16(a, b, c, 0, 0, 0);
}

// async global->LDS, 16B per lane; dest = wave-uniform base + lane*16
__device__ __forceinline__ void gload_lds16(const u16* g, u16* l) {
  __builtin_amdgcn_global_load_lds(
      (const __attribute__((address_space(1))) u32*)(uintptr_t)g,
      (__attribute__((address_space(3))) u32*)(u32)(uintptr_t)l,
      16, 0, 0);
}

// ---------- block-wide reduction of 4 values over 256 threads ----------
__device__ __forceinline__ void block_reduce4(float& a, float& b, float& c, float& d) {
  #pragma unroll
  for (int off = 32; off > 0; off >>= 1) {
    a += __shfl_down(a, off, 64);
    b += __shfl_down(b, off, 64);
    c += __shfl_down(c, off, 64);
    d += __shfl_down(d, off, 64);
  }
  __shared__ float red[4][4];
  int wid = threadIdx.x >> 6;
  int lane = threadIdx.x & 63;
  if (lane == 0) { red[0][wid] = a; red[1][wid] = b; red[2][wid] = c; red[3][wid] = d; }
  __syncthreads();
  a = red[0][0] + red[0][1] + red[0][2] + red[0][3];
  b = red[1][0] + red[1][1] + red[1][2] + red[1][3];
  c = red[2][0] + red[2][1] + red[2][2] + red[2][3];
  d = red[3][0] + red[3][1] + red[3][2] + red[3][3];
}

// ---------- K1 (fused): blocks 0..8191 = LayerNorm-1; 8192..8575 = weight prep.
// The two bodies are data-independent (ln1: x -> xnr/xni; wprep: Wq/Wk/Wv -> wT);
// fusing removes one stream-serialized launch + tail. Branch is block-uniform.
__global__ __launch_bounds__(256) void prep_kernel(
    const float* __restrict__ x, const float* __restrict__ w, const float* __restrict__ bi,
    u16* __restrict__ xnr, u16* __restrict__ xni,
    const float* __restrict__ Wq, const float* __restrict__ Wk, const float* __restrict__ Wv,
    u16* __restrict__ wT) {
  const int tid = threadIdx.x;
  if (blockIdx.x < BT_) {
    // ---- ln1 body: LayerNorm over F per (b,t,plane); emit bf16 real/imag
    const int row = blockIdx.x;
    const int f = tid;
    float2 xv = reinterpret_cast<const float2*>(x)[row * F_ + f];
    float sr = xv.x, si = xv.y, sr2 = xv.x * xv.x, si2 = xv.y * xv.y;
    block_reduce4(sr, si, sr2, si2);
    const float inv = 1.0f / F_;
    float mr = sr * inv, mi = si * inv;
    float vr = sr2 * inv - mr * mr, vi = si2 * inv - mi * mi;
    float rr = rsqrtf(vr + EPS), ri = rsqrtf(vi + EPS);
    float ww = w[f], bb = bi[f];
    xnr[row * F_ + f] = f2bf((xv.x - mr) * rr * ww + bb);
    xni[row * F_ + f] = f2bf((xv.y - mi) * ri * ww + bb);
  } else {
    // ---- wprep body: transpose+convert W[z][f][h] (f32) -> wT[z][h][f] (bf16)
    const int wid = blockIdx.x - BT_;   // 0..383
    const int z = wid >> 4;             // 0..23
    const int r4 = wid & 15;
    const int ft = (r4 & 3) * 64;
    const int ht = (r4 >> 2) * 64;
    const int m = z >> 3, n = z & 7;
    const float* W = (m == 0 ? Wq : (m == 1 ? Wk : Wv)) + (size_t)n * F_ * H_;
    __shared__ __align__(16) u16 Ts[64][72];

    #pragma unroll
    for (int i = 0; i < 4; i++) {
      int id = tid + i * 256;
      int r = id >> 4, c4 = (id & 15) * 4;
      float4 p = *reinterpret_cast<const float4*>(&W[(size_t)(ft + r) * H_ + ht + c4]);
      Ts[r][c4 + 0] = f2bf(p.x); Ts[r][c4 + 1] = f2bf(p.y);
      Ts[r][c4 + 2] = f2bf(p.z); Ts[r][c4 + 3] = f2bf(p.w);
    }
    __syncthreads();
    u16* op = wT + (size_t)z * F_ * H_ + (size_t)ht * F_ + ft;
    #pragma unroll
    for (int i = 0; i < 2; i++) {
      int id = tid + i * 256;
      int hl = id & 63, g = id >> 6;
      u16 tmp[8];
      #pragma unroll
      for (int j = 0; j < 8; j++) tmp[j] = Ts[g * 8 + j][hl];
      *reinterpret_cast<uint4*>(op + (size_t)hl * F_ + g * 8) =
          *reinterpret_cast<const uint4*>(tmp);
    }
  }
}

// ---------- K2b: QKV projections — bf16 MFMA GEMM, 128x256 tile (full H), BK=64 ----------
__global__ __launch_bounds__(256, 2) void qkv_kernel(
    const u16* __restrict__ xnr, const u16* __restrict__ xni, const u16* __restrict__ wT,
    const float* __restrict__ bq, const float* __restrict__ bk, const float* __restrict__ bv,
    u16* __restrict__ qo, u16* __restrict__ ko, u16* __restrict__ vTo) {
  const int z = blockIdx.y;
  const int m = z >> 3, n = z & 7;
  int sel; const float* bias; u16* out;
  if (m == 0)      { sel = (n >> 1) & 1;  bias = bq; out = qo + (size_t)n * BT_ * H_; }
  else if (m == 1) { sel = n & 1;         bias = bk; out = ko + (size_t)n * BT_ * H_; }
  else             { sel = __popc(n) & 1; bias = bv; out = nullptr; }
  const float osc = (m == 0) ? SCALE_L2E : 1.0f;   // q pre-scaled by 1/16*log2(e)
  const u16* A = sel ? xni : xnr;
  const u16* wp = wT + (size_t)z * F_ * H_;
  bias += n * H_;
  const int rowbase = blockIdx.x * 128;

  __shared__ __align__(16) u16 As[2][128 * 32];   // 16 KB
  __shared__ __align__(16) u16 Bs[2][256 * 32];   // 32 KB
  __shared__ __align__(16) u16 Epi[4][1536];      // q/k: [16][72]; v: [64][24]

  const int tid = threadIdx.x;
  const int wv = tid >> 6, lane = tid & 63;
  const int quad = lane >> 4, l16 = lane & 15;
  const int wrow = wv >> 1, wcol = wv & 1;        // wave: 64 rows x 128 cols

  f32x4 acc[4][8];
  #pragma unroll
  for (int i = 0; i < 4; i++)
    #pragma unroll
    for (int j = 0; j < 8; j++) acc[i][j] = (f32x4){0.f, 0.f, 0.f, 0.f};

  const int ar = tid >> 2;            // A staging: row tid>>2, k-chunk (tid&3)*8
  const int ak = (tid & 3) * 8;

  #pragma unroll 1
  for (int kb = 0; kb < F_; kb += 64) {
    #pragma unroll
    for (int h = 0; h < 2; h++) {
      // A half: 128x32 = 8KB = 2 DMA groups
      gload_lds16(A + (size_t)(rowbase + ar) * F_ + kb + h * 32 + ak,
                  &As[h][tid * 8]);
      gload_lds16(A + (size_t)(rowbase + 64 + ar) * F_ + kb + h * 32 + ak,
                  &As[h][2048 + tid * 8]);
      // B half: 256x32 = 16KB = 4 DMA groups
      #pragma unroll
      for (int c = 0; c < 4; c++)
        gload_lds16(wp + (size_t)(c * 64 + ar) * F_ + kb + h * 32 + ak,
                    &Bs[h][c * 2048 + tid * 8]);
    }
    __syncthreads();
    #pragma unroll
    for (int h = 0; h < 2; h++) {
      bf16x8 a[4], b[8];
      #pragma unroll
      for (int mi = 0; mi < 4; mi++)
        a[mi] = *reinterpret_cast<const bf16x8*>(
            &As[h][(wrow * 64 + mi * 16 + l16) * 32 + quad * 8]);
      #pragma unroll
      for (int nj = 0; nj < 8; nj++)
        b[nj] = *reinterpret_cast<const bf16x8*>(
            &Bs[h][(wcol * 128 + nj * 16 + l16) * 32 + quad * 8]);
      #pragma unroll
      for (int mi = 0; mi < 4; mi++)
        #pragma unroll
        for (int nj = 0; nj < 8; nj++)
          acc[mi][nj] = mfma16(a[mi], b[nj], acc[mi][nj]);
    }
    __syncthreads();
  }

  float bias8[8];
  #pragma unroll
  for (int nj = 0; nj < 8; nj++)
    bias8[nj] = bias[wcol * 128 + nj * 16 + l16];

  if (m != 2) {   // q/k: row-major store, two 64-col passes
    #pragma unroll
    for (int pass = 0; pass < 2; pass++) {
      #pragma unroll
      for (int mi = 0; mi < 4; mi++) {
        #pragma unroll
        for (int nj4 = 0; nj4 < 4; nj4++) {
          int nj = pass * 4 + nj4;
          #pragma unroll
          for (int r = 0; r < 4; r++)
            Epi[wv][(quad * 4 + r) * 72 + nj4 * 16 + l16] =
                f2bf((acc[mi][nj][r] + bias8[nj]) * osc);
        }
        int row = rowbase + wrow * 64 + mi * 16 + l16;
        uint4 v0 = *reinterpret_cast<const uint4*>(&Epi[wv][l16 * 72 + quad * 16]);
        uint4 v1 = *reinterpret_cast<const uint4*>(&Epi[wv][l16 * 72 + quad * 16 + 8]);
        u16* op = out + (size_t)row * H_ + wcol * 128 + pass * 64 + quad * 16;
        *reinterpret_cast<uint4*>(op) = v0;
        *reinterpret_cast<uint4*>(op + 8) = v1;
      }
    }
  } else {        // v: transposed store into vT[n][h][bt], two 64-h passes
    #pragma unroll
    for (int pass = 0; pass < 2; pass++) {
      #pragma unroll
      for (int mi = 0; mi < 4; mi++) {
        #pragma unroll
        for (int nj4 = 0; nj4 < 4; nj4++) {
          int nj = pass * 4 + nj4;
          #pragma unroll
          for (int r = 0; r < 4; r++)
            Epi[wv][(nj4 * 16 + l16) * 24 + quad * 4 + r] =
                f2bf(acc[mi][nj][r] + bias8[nj]);
        }
        int hloc = lane;                  // 0..63
        uint4 w0 = *reinterpret_cast<const uint4*>(&Epi[wv][hloc * 24]);
        uint4 w1 = *reinterpret_cast<const uint4*>(&Epi[wv][hloc * 24 + 8]);
        u16* op = vTo + (size_t)n * H_ * BT_ +
                  (size_t)(wcol * 128 + pass * 64 + hloc) * BT_ +
                  rowbase + wrow * 64 + mi * 16;
        *reinterpret_cast<uint4*>(op) = w0;
        *reinterpret_cast<uint4*>(op + 8) = w1;
      }
    }
  }
}

// ---------- K3: MFMA flash attention ----------
// R22 == R21 (session best: attn 102.0 us, total 170.3 us). Structure:
// counted vmcnt, split K/V prefetch (distance ~1 iter each), raw v_exp_f32
// softmax (log2e folded into q pre-scale in qkv), full-depth XOR swizzles.
//   QK(kt) | softmax | B1(lgkm0) | stage_k(kt+2,c) | PV(kt) |
//   B2(vmcnt 4/0) | stage_v(kt+2,c)
// Cost model (per block-iter ~7.65K cyc): LDS pipe ~4.7K (K/V frags 3K,
// Ps round-trip 1.1K, DMA 0.5K) is the structural bound at 2 waves/SIMD
// (LDS 149.5 KB -> 1 block/CU). Swapped-QK/in-reg-P blocked by the kh<->hh
// wave remix; KVBLK=32 re-tiling degenerates; merge arc spills (R15-R18).
__global__ __launch_bounds__(512, 2) void attn_kernel(
    const u16* __restrict__ q, const u16* __restrict__ k, const u16* __restrict__ vT,
    u16* __restrict__ obuf) {
  const int fid = blockIdx.x;        // 0..511
  const int qt = fid >> 6;           // 0..7 : 128 query rows
  const int nb = fid & 63;           // n*8 + b ; XCD = nb & 7
  const int n = nb >> 3, b = nb & 7;
  const int tid = threadIdx.x;
  const int wv = tid >> 6, lane = tid & 63;
  const int hi = lane >> 5, l32 = lane & 31;
  const int qh = wv >> 1;            // q 32-row group (0..3)
  const int kh = wv & 1;             // QK: key-half (32 keys)
  const int hh = wv & 1;             // PV: h-half (128 h)

  const size_t base = (size_t)nb * T_ * H_;
  const u16* qp = q + base;          // pre-scaled by SCALE_L2E
  const u16* kp = k + base;
  const u16* vtp = vT + ((size_t)n * H_ * B_ + b) * T_;

  __shared__ __align__(16) u16 Ks[2][64][256];   // 64 KB, 5-bit XOR swizzle
  __shared__ __align__(16) u16 Vs[2][64][256];   // 64 KB, packed-4h + 3-bit XOR
  __shared__ __align__(16) u16 Ps[4][32][72];    // 18,432 B (cols 64..67: l-sums)

  const int qrow0 = qt * 128 + qh * 32;
  bf16x8 qf[16];
  #pragma unroll
  for (int kc = 0; kc < 16; kc++)
    qf[kc] = *reinterpret_cast<const bf16x8*>(
        qp + (size_t)(qrow0 + l32) * H_ + kc * 16 + hi * 8);

  f32x16 o[4];
  #pragma unroll
  for (int ot = 0; ot < 4; ot++)
    #pragma unroll
    for (int r = 0; r < 16; r++) o[ot][r] = 0.f;
  float lper[16];
  #pragma unroll
  for (int r = 0; r < 16; r++) lper[r] = 0.f;

  // K staging: 32 DMA instrs (4/wave), each fills 2 rows (512B each).
  // Lane l -> row 2*idx+(l>>5), 16B slot (l&31). Slot s of row r holds
  // K[r][(s ^ (r&31))*8 ..], so source col = ((l&31) ^ (row&31))*8.
  auto stage_k = [&](int ktN, int buf) {
    #pragma unroll
    for (int i = 0; i < 4; i++) {
      int idx = wv * 4 + i;
      int row = 2 * idx + hi;
      const u16* src = kp + (size_t)(ktN * 64 + row) * H_ +
                       ((l32 ^ (row & 31)) * 8);
      gload_lds16(src, &Ks[buf][2 * idx][0]);
    }
  };
  // V staging: 32 DMA instrs (4/wave), each fills 2 physical rows.
  // Physical row p holds h = p*4..p*4+3 (64 keys each). Slot s of row p
  // holds unswizzled block u = s ^ (p&7); u -> h = p*4 + (u>>3),
  // key0 = (u&7)*8.  Lane l: p = 2*idx+(l>>5), s = l&31.
  auto stage_v = [&](int ktN, int buf) {
    #pragma unroll
    for (int i = 0; i < 4; i++) {
      int idx = wv * 4 + i;
      int p = 2 * idx + hi;
      int u = l32 ^ (p & 7);
      const u16* src = vtp + (size_t)(p * 4 + (u >> 3)) * BT_ +
                       ktN * 64 + (u & 7) * 8;
      gload_lds16(src, &Vs[buf][2 * idx][0]);
    }
  };

  // Prologue: stage tiles 0 and 1; wait only tile 0 (own 8 newest = tile 1).
  stage_k(0, 0); stage_v(0, 0);
  stage_k(1, 1); stage_v(1, 1);
  asm volatile("s_waitcnt vmcnt(8)" ::: "memory");
  __builtin_amdgcn_s_barrier();
  __builtin_amdgcn_sched_barrier(0);

  const int krow = kh * 32 + l32;

  #pragma unroll 1
  for (int kt = 0; kt < 16; kt++) {
    const int c = kt & 1;

    // ---- QK phase: reads Ks[c] (tile kt; landed: vmcnt+barrier last iter)
    f32x16 sa, sb;
    #pragma unroll
    for (int r = 0; r < 16; r++) { sa[r] = 0.f; sb[r] = 0.f; }
    __builtin_amdgcn_s_setprio(1);
    #pragma unroll
    for (int kc = 0; kc < 16; kc += 2) {
      // fragment blocks kc*2+hi and (kc+1)*2+hi, swizzled by ^l32 (krow&31)
      bf16x8 kfa = *reinterpret_cast<const bf16x8*>(
          &Ks[c][krow][(((kc * 2 + hi) ^ l32) * 8)]);
      bf16x8 kfb = *reinterpret_cast<const bf16x8*>(
          &Ks[c][krow][(((kc * 2 + 2 + hi) ^ l32) * 8)]);
      sa = mfma32(qf[kc], kfa, sa);
      sb = mfma32(qf[kc + 1], kfb, sb);
    }
    __builtin_amdgcn_s_setprio(0);

    #pragma unroll
    for (int r = 0; r < 16; r++) {
      float p = __builtin_amdgcn_exp2f(sa[r] + sb[r]);  // log2e pre-folded
      lper[r] += p;
      Ps[qh][(r & 3) + 8 * (r >> 2) + 4 * hi][kh * 32 + l32] = f2bf(p);
    }

    // ---- B1: Ps writes visible; Ks[c] readers (all waves) retired.
    asm volatile("s_waitcnt lgkmcnt(0)" ::: "memory");
    __builtin_amdgcn_s_barrier();
    __builtin_amdgcn_sched_barrier(0);

    // K-stage(kt+2 -> c): safe (Ks[c] last read before B1). Drains ~2 iters
    // from now; never force-drained by a barrier.
    if (kt < 14) stage_k(kt + 2, c);

    // ---- PV phase: reads Ps + Vs[c]
    bf16x8 pa[4];
    #pragma unroll
    for (int kc2 = 0; kc2 < 4; kc2++)
      pa[kc2] = *reinterpret_cast<const bf16x8*>(
          &Ps[qh][l32][kc2 * 16 + hi * 8]);
    __builtin_amdgcn_s_setprio(1);
    #pragma unroll
    for (int ot = 0; ot < 4; ot++) {
      const int p = hh * 32 + ot * 8 + (l32 >> 2);
      #pragma unroll
      for (int kc2 = 0; kc2 < 4; kc2++) {
        int s = ((l32 & 3) * 8 + kc2 * 2 + hi) ^ (l32 >> 2);
        bf16x8 vf = *reinterpret_cast<const bf16x8*>(&Vs[c][p][s * 8]);
        o[ot] = mfma32(pa[kc2], vf, o[ot]);
      }
    }
    __builtin_amdgcn_s_setprio(0);

    // ---- B2: own K/V(kt+1) landed (allow only K(kt+2)'s 4 loads in flight);
    // barrier -> ALL waves' tile-(kt+1) slices landed.  Vs[c]/Ps readers
    // retired here.  Tail iters drain fully (no further stages to count).
    if (kt < 14) {
      asm volatile("s_waitcnt vmcnt(4)" ::: "memory");
    } else {
      asm volatile("s_waitcnt vmcnt(0)" ::: "memory");
    }
    __builtin_amdgcn_s_barrier();
    __builtin_amdgcn_sched_barrier(0);

    // V-stage(kt+2 -> c): safe (Vs[c] last read before B2).
    if (kt < 14) stage_v(kt + 2, c);
  }

  #pragma unroll
  for (int r = 0; r < 16; r++) {
    #pragma unroll
    for (int off = 1; off < 32; off <<= 1)
      lper[r] += __shfl_xor(lper[r], off, 64);
  }
  if (l32 == 0) {
    #pragma unroll
    for (int r = 0; r < 16; r++) {
      int row = (r & 3) + 8 * (r >> 2) + 4 * hi;
      *reinterpret_cast<float*>(&Ps[qh][row][64 + 2 * kh]) = lper[r];
    }
  }
  __syncthreads();

  float invl[16];
  #pragma unroll
  for (int r = 0; r < 16; r++) {
    int row = (r & 3) + 8 * (r >> 2) + 4 * hi;
    float l0 = *reinterpret_cast<const float*>(&Ps[qh][row][64]);
    float l1 = *reinterpret_cast<const float*>(&Ps[qh][row][66]);
    invl[r] = 1.0f / (l0 + l1);
  }

  u16* Ew = reinterpret_cast<u16*>(&Ks[0][0][0]) + wv * 1280;   // 8x1280 u16
  const int grow = b * 1024 + qrow0 + l32;
  #pragma unroll
  for (int ot = 0; ot < 4; ot++) {
    #pragma unroll
    for (int r = 0; r < 16; r++) {
      int row = (r & 3) + 8 * (r >> 2) + 4 * hi;
      Ew[row * 40 + l32] = f2bf(o[ot][r] * invl[r]);
    }
    int ht = hh * 4 + ot;
    uint4 v0 = *reinterpret_cast<const uint4*>(&Ew[l32 * 40 + hi * 16]);
    uint4 v1 = *reinterpret_cast<const uint4*>(&Ew[l32 * 40 + hi * 16 + 8]);
    u16* op = obuf + (((size_t)n * 8 + ht) * BT_ + grow) * 32 + hi * 16;
    *reinterpret_cast<uint4*>(op) = v0;
    *reinterpret_cast<uint4*>(op + 8) = v1;
  }
}

// ---------- K4: combine 8 branches (signed) + LayerNorm over H ----------
__global__ __launch_bounds__(256) void combine_ln2_kernel(
    const u16* __restrict__ obuf, const float* __restrict__ w,
    const float* __restrict__ bi, float* __restrict__ out) {
  const int row = blockIdx.x;
  const int h = threadIdx.x;
  float o[8];
  #pragma unroll
  for (int nn = 0; nn < 8; nn++)
    o[nn] = bf1(obuf[(((size_t)nn * 8 + (h >> 5)) * BT_ + row) * 32 + (h & 31)]);
  float re = o[0] - o[1] - o[2] - o[3];
  float im = o[4] + o[5] + o[6] - o[7];
  float sr = re, si = im, sr2 = re * re, si2 = im * im;
  block_reduce4(sr, si, sr2, si2);
  const float inv = 1.0f / H_;
  float mr = sr * inv, mi = si * inv;
  float vr = sr2 * inv - mr * mr, vi = si2 * inv - mi * mi;
  float rr = rsqrtf(vr + EPS), ri = rsqrtf(vi + EPS);
  float ww = w[h], bb = bi[h];
  float2 res;
  res.x = (re - mr) * rr * ww + bb;
  res.y = (im - mi) * ri * ww + bb;
  reinterpret_cast<float2*>(out)[(size_t)row * H_ + h] = res;
}

extern "C" void kernel_launch(void* const* d_in, const int* in_sizes, int n_in,
                              void* d_out, int out_size, void* d_ws, size_t ws_size,
                              hipStream_t stream) {
  const float* x    = (const float*)d_in[0];
  const float* Wq   = (const float*)d_in[1];
  const float* bq   = (const float*)d_in[2];
  const float* Wk   = (const float*)d_in[3];
  const float* bk   = (const float*)d_in[4];
  const float* Wv   = (const float*)d_in[5];
  const float* bv   = (const float*)d_in[6];
  const float* ln1w = (const float*)d_in[7];
  const float* ln1b = (const float*)d_in[8];
  const float* ln2w = (const float*)d_in[9];
  const float* ln2b = (const float*)d_in[10];

  // Workspace (128 MB), lifetime-aliased:
  //  [0,8)  xn  (dead after qkv)  |  [0,32)  obuf (written by attn, after qkv)
  //  [8,11) wT  (dead after qkv)
  //  [32,64) vT ; [64,96) q ; [96,128) k
  char* ws = (char*)d_ws;
  u16* xnr  = (u16*)(ws);
  u16* xni  = (u16*)(ws + (4ull  << 20));
  u16* wTb  = (u16*)(ws + (8ull  << 20));
  u16* obuf = (u16*)(ws);
  u16* vT   = (u16*)(ws + (32ull << 20));
  u16* qbuf = (u16*)(ws + (64ull << 20));
  u16* kbuf = (u16*)(ws + (96ull << 20));

  prep_kernel<<<BT_ + 384, 256, 0, stream>>>(x, ln1w, ln1b, xnr, xni,
                                             Wq, Wk, Wv, wTb);
  qkv_kernel<<<dim3(64, 24), 256, 0, stream>>>(xnr, xni, wTb, bq, bk, bv,
                                               qbuf, kbuf, vT);
  attn_kernel<<<dim3(512), 512, 0, stream>>>(qbuf, kbuf, vT, obuf);
  combine_ln2_kernel<<<BT_, 256, 0, stream>>>(obuf, ln2w, ln2b, (float*)d_out);
}

// Round 14
// 165.832 us; speedup vs baseline: 2.3545x; 1.0068x over previous
//
#include <hip/hip_runtime.h>
#include <math.h>

#define B_ 8
#define T_ 1024
#define F_ 256
#define H_ 256
#define BT_ (B_*T_)          // 8192
constexpr float EPS = 1e-5f;
// 1/sqrt(256) * log2(e), folded into qbuf: softmax uses raw v_exp_f32 (exp2).
constexpr float SCALE_L2E = 0.09016844005555963f;

typedef unsigned int u32;
typedef unsigned short u16;
typedef __attribute__((ext_vector_type(8))) short bf16x8;    // 8 bf16 = 4 VGPRs
typedef __attribute__((ext_vector_type(4))) float f32x4;
typedef __attribute__((ext_vector_type(16))) float f32x16;

// ---------- bf16 helpers ----------
__device__ __forceinline__ float bf1(u16 p) { return __uint_as_float(((u32)p) << 16); }
__device__ __forceinline__ u16 f2bf(float f) {
  u32 u = __float_as_uint(f);
  u32 r = u + 0x7FFFu + ((u >> 16) & 1u);   // RNE
  return (u16)(r >> 16);
}

__device__ __forceinline__ f32x4 mfma16(bf16x8 a, bf16x8 b, f32x4 c) {
  return __builtin_amdgcn_mfma_f32_16x16x32_bf16(a, b, c, 0, 0, 0);
}
__device__ __forceinline__ f32x16 mfma32(bf16x8 a, bf16x8 b, f32x16 c) {
  return __builtin_amdgcn_mfma_f32_32x32x16_bf16(a, b, c, 0, 0, 0);
}

// async global->LDS, 16B per lane; dest = wave-uniform base + lane*16
__device__ __forceinline__ void gload_lds16(const u16* g, u16* l) {
  __builtin_amdgcn_global_load_lds(
      (const __attribute__((address_space(1))) u32*)(uintptr_t)g,
      (__attribute__((address_space(3))) u32*)(u32)(uintptr_t)l,
      16, 0, 0);
}

// ---------- block-wide reduction of 4 values over 256 threads ----------
__device__ __forceinline__ void block_reduce4(float& a, float& b, float& c, float& d) {
  #pragma unroll
  for (int off = 32; off > 0; off >>= 1) {
    a += __shfl_down(a, off, 64);
    b += __shfl_down(b, off, 64);
    c += __shfl_down(c, off, 64);
    d += __shfl_down(d, off, 64);
  }
  __shared__ float red[4][4];
  int wid = threadIdx.x >> 6;
  int lane = threadIdx.x & 63;
  if (lane == 0) { red[0][wid] = a; red[1][wid] = b; red[2][wid] = c; red[3][wid] = d; }
  __syncthreads();
  a = red[0][0] + red[0][1] + red[0][2] + red[0][3];
  b = red[1][0] + red[1][1] + red[1][2] + red[1][3];
  c = red[2][0] + red[2][1] + red[2][2] + red[2][3];
  d = red[3][0] + red[3][1] + red[3][2] + red[3][3];
}

// ---------- K1 (fused): blocks 0..8191 = LayerNorm-1; 8192..8575 = weight prep.
__global__ __launch_bounds__(256) void prep_kernel(
    const float* __restrict__ x, const float* __restrict__ w, const float* __restrict__ bi,
    u16* __restrict__ xnr, u16* __restrict__ xni,
    const float* __restrict__ Wq, const float* __restrict__ Wk, const float* __restrict__ Wv,
    u16* __restrict__ wT) {
  const int tid = threadIdx.x;
  if (blockIdx.x < BT_) {
    // ---- ln1 body: LayerNorm over F per (b,t,plane); emit bf16 real/imag
    const int row = blockIdx.x;
    const int f = tid;
    float2 xv = reinterpret_cast<const float2*>(x)[row * F_ + f];
    float sr = xv.x, si = xv.y, sr2 = xv.x * xv.x, si2 = xv.y * xv.y;
    block_reduce4(sr, si, sr2, si2);
    const float inv = 1.0f / F_;
    float mr = sr * inv, mi = si * inv;
    float vr = sr2 * inv - mr * mr, vi = si2 * inv - mi * mi;
    float rr = rsqrtf(vr + EPS), ri = rsqrtf(vi + EPS);
    float ww = w[f], bb = bi[f];
    xnr[row * F_ + f] = f2bf((xv.x - mr) * rr * ww + bb);
    xni[row * F_ + f] = f2bf((xv.y - mi) * ri * ww + bb);
  } else {
    // ---- wprep body: transpose+convert W[z][f][h] (f32) -> wT[z][h][f] (bf16)
    const int wid = blockIdx.x - BT_;   // 0..383
    const int z = wid >> 4;             // 0..23
    const int r4 = wid & 15;
    const int ft = (r4 & 3) * 64;
    const int ht = (r4 >> 2) * 64;
    const int m = z >> 3, n = z & 7;
    const float* W = (m == 0 ? Wq : (m == 1 ? Wk : Wv)) + (size_t)n * F_ * H_;
    __shared__ __align__(16) u16 Ts[64][72];

    #pragma unroll
    for (int i = 0; i < 4; i++) {
      int id = tid + i * 256;
      int r = id >> 4, c4 = (id & 15) * 4;
      float4 p = *reinterpret_cast<const float4*>(&W[(size_t)(ft + r) * H_ + ht + c4]);
      Ts[r][c4 + 0] = f2bf(p.x); Ts[r][c4 + 1] = f2bf(p.y);
      Ts[r][c4 + 2] = f2bf(p.z); Ts[r][c4 + 3] = f2bf(p.w);
    }
    __syncthreads();
    u16* op = wT + (size_t)z * F_ * H_ + (size_t)ht * F_ + ft;
    #pragma unroll
    for (int i = 0; i < 2; i++) {
      int id = tid + i * 256;
      int hl = id & 63, g = id >> 6;
      u16 tmp[8];
      #pragma unroll
      for (int j = 0; j < 8; j++) tmp[j] = Ts[g * 8 + j][hl];
      *reinterpret_cast<uint4*>(op + (size_t)hl * F_ + g * 8) =
          *reinterpret_cast<const uint4*>(tmp);
    }
  }
}

// ---------- K2b: QKV projections — bf16 MFMA GEMM, 128x256 tile (full H) ----------
// R23: counted-vmcnt double-buffer pipeline (attn-R14-proven template).
// Old loop force-drained each 48KB stage at the next __syncthreads (vmcnt(0))
// -> 8 exposed L2/HBM latencies per block. Now As/Bs [2] are TRUE double
// buffers of BK=32 tiles (8 K-steps):
//   prologue: stage(0,0), stage(1,1); vmcnt(6); barrier
//   step t:   compute buf[c] | B1(lgkm0+bar) | stage(t+2,c) |
//             B2(vmcnt(6) if t<6 else 0, +bar)
// Ledger: in-flight after stage(t+2) <= 12; vmcnt(6) leaves only t+2's 6
// -> tile t+1 landed for ALL waves (barrier); every buffer overwrite is one
// full barrier after all waves' last reads (B1).
__global__ __launch_bounds__(256, 2) void qkv_kernel(
    const u16* __restrict__ xnr, const u16* __restrict__ xni, const u16* __restrict__ wT,
    const float* __restrict__ bq, const float* __restrict__ bk, const float* __restrict__ bv,
    u16* __restrict__ qo, u16* __restrict__ ko, u16* __restrict__ vTo) {
  const int z = blockIdx.y;
  const int m = z >> 3, n = z & 7;
  int sel; const float* bias; u16* out;
  if (m == 0)      { sel = (n >> 1) & 1;  bias = bq; out = qo + (size_t)n * BT_ * H_; }
  else if (m == 1) { sel = n & 1;         bias = bk; out = ko + (size_t)n * BT_ * H_; }
  else             { sel = __popc(n) & 1; bias = bv; out = nullptr; }
  const float osc = (m == 0) ? SCALE_L2E : 1.0f;   // q pre-scaled by 1/16*log2(e)
  const u16* A = sel ? xni : xnr;
  const u16* wp = wT + (size_t)z * F_ * H_;
  bias += n * H_;
  const int rowbase = blockIdx.x * 128;

  __shared__ __align__(16) u16 As[2][128 * 32];   // 16 KB, dbuf of BK=32 tiles
  __shared__ __align__(16) u16 Bs[2][256 * 32];   // 32 KB, dbuf of BK=32 tiles
  __shared__ __align__(16) u16 Epi[4][1536];      // q/k: [16][72]; v: [64][24]

  const int tid = threadIdx.x;
  const int wv = tid >> 6, lane = tid & 63;
  const int quad = lane >> 4, l16 = lane & 15;
  const int wrow = wv >> 1, wcol = wv & 1;        // wave: 64 rows x 128 cols

  f32x4 acc[4][8];
  #pragma unroll
  for (int i = 0; i < 4; i++)
    #pragma unroll
    for (int j = 0; j < 8; j++) acc[i][j] = (f32x4){0.f, 0.f, 0.f, 0.f};

  const int ar = tid >> 2;            // staging: row tid>>2, k-chunk (tid&3)*8
  const int ak = (tid & 3) * 8;

  // stage K-tile t (cols t*32..t*32+31) into buffer buf: 6 DMA instr-groups.
  auto stage = [&](int t, int buf) {
    const int kb = t * 32;
    gload_lds16(A + (size_t)(rowbase + ar) * F_ + kb + ak, &As[buf][tid * 8]);
    gload_lds16(A + (size_t)(rowbase + 64 + ar) * F_ + kb + ak,
                &As[buf][2048 + tid * 8]);
    #pragma unroll
    for (int c = 0; c < 4; c++)
      gload_lds16(wp + (size_t)(c * 64 + ar) * F_ + kb + ak,
                  &Bs[buf][c * 2048 + tid * 8]);
  };

  stage(0, 0);
  stage(1, 1);
  asm volatile("s_waitcnt vmcnt(6)" ::: "memory");   // tile 0 landed
  __builtin_amdgcn_s_barrier();
  __builtin_amdgcn_sched_barrier(0);

  #pragma unroll 1
  for (int t = 0; t < 8; t++) {
    const int c = t & 1;

    // ---- compute tile t from As[c]/Bs[c]: 12 ds_read_b128 + 32 mfma16
    bf16x8 a[4], b[8];
    #pragma unroll
    for (int mi = 0; mi < 4; mi++)
      a[mi] = *reinterpret_cast<const bf16x8*>(
          &As[c][(wrow * 64 + mi * 16 + l16) * 32 + quad * 8]);
    #pragma unroll
    for (int nj = 0; nj < 8; nj++)
      b[nj] = *reinterpret_cast<const bf16x8*>(
          &Bs[c][(wcol * 128 + nj * 16 + l16) * 32 + quad * 8]);
    __builtin_amdgcn_s_setprio(1);
    #pragma unroll
    for (int mi = 0; mi < 4; mi++)
      #pragma unroll
      for (int nj = 0; nj < 8; nj++)
        acc[mi][nj] = mfma16(a[mi], b[nj], acc[mi][nj]);
    __builtin_amdgcn_s_setprio(0);

    // ---- B1: all waves' reads of buf c retired -> c may be overwritten
    asm volatile("s_waitcnt lgkmcnt(0)" ::: "memory");
    __builtin_amdgcn_s_barrier();
    __builtin_amdgcn_sched_barrier(0);

    if (t < 6) stage(t + 2, c);

    // ---- B2: tile t+1 resident for all waves (counted vmcnt, no drain)
    if (t < 6) {
      asm volatile("s_waitcnt vmcnt(6)" ::: "memory");
    } else {
      asm volatile("s_waitcnt vmcnt(0)" ::: "memory");
    }
    __builtin_amdgcn_s_barrier();
    __builtin_amdgcn_sched_barrier(0);
  }

  float bias8[8];
  #pragma unroll
  for (int nj = 0; nj < 8; nj++)
    bias8[nj] = bias[wcol * 128 + nj * 16 + l16];

  if (m != 2) {   // q/k: row-major store, two 64-col passes
    #pragma unroll
    for (int pass = 0; pass < 2; pass++) {
      #pragma unroll
      for (int mi = 0; mi < 4; mi++) {
        #pragma unroll
        for (int nj4 = 0; nj4 < 4; nj4++) {
          int nj = pass * 4 + nj4;
          #pragma unroll
          for (int r = 0; r < 4; r++)
            Epi[wv][(quad * 4 + r) * 72 + nj4 * 16 + l16] =
                f2bf((acc[mi][nj][r] + bias8[nj]) * osc);
        }
        int row = rowbase + wrow * 64 + mi * 16 + l16;
        uint4 v0 = *reinterpret_cast<const uint4*>(&Epi[wv][l16 * 72 + quad * 16]);
        uint4 v1 = *reinterpret_cast<const uint4*>(&Epi[wv][l16 * 72 + quad * 16 + 8]);
        u16* op = out + (size_t)row * H_ + wcol * 128 + pass * 64 + quad * 16;
        *reinterpret_cast<uint4*>(op) = v0;
        *reinterpret_cast<uint4*>(op + 8) = v1;
      }
    }
  } else {        // v: transposed store into vT[n][h][bt], two 64-h passes
    #pragma unroll
    for (int pass = 0; pass < 2; pass++) {
      #pragma unroll
      for (int mi = 0; mi < 4; mi++) {
        #pragma unroll
        for (int nj4 = 0; nj4 < 4; nj4++) {
          int nj = pass * 4 + nj4;
          #pragma unroll
          for (int r = 0; r < 4; r++)
            Epi[wv][(nj4 * 16 + l16) * 24 + quad * 4 + r] =
                f2bf(acc[mi][nj][r] + bias8[nj]);
        }
        int hloc = lane;                  // 0..63
        uint4 w0 = *reinterpret_cast<const uint4*>(&Epi[wv][hloc * 24]);
        uint4 w1 = *reinterpret_cast<const uint4*>(&Epi[wv][hloc * 24 + 8]);
        u16* op = vTo + (size_t)n * H_ * BT_ +
                  (size_t)(wcol * 128 + pass * 64 + hloc) * BT_ +
                  rowbase + wrow * 64 + mi * 16;
        *reinterpret_cast<uint4*>(op) = w0;
        *reinterpret_cast<uint4*>(op + 8) = w1;
      }
    }
  }
}

// ---------- K3: MFMA flash attention ----------
// R23 == R21/R22 attn (session best: 102.7 us). Counted vmcnt, split K/V
// prefetch, raw v_exp_f32 softmax (log2e pre-folded), full-depth XOR swizzles.
__global__ __launch_bounds__(512, 2) void attn_kernel(
    const u16* __restrict__ q, const u16* __restrict__ k, const u16* __restrict__ vT,
    u16* __restrict__ obuf) {
  const int fid = blockIdx.x;        // 0..511
  const int qt = fid >> 6;           // 0..7 : 128 query rows
  const int nb = fid & 63;           // n*8 + b ; XCD = nb & 7
  const int n = nb >> 3, b = nb & 7;
  const int tid = threadIdx.x;
  const int wv = tid >> 6, lane = tid & 63;
  const int hi = lane >> 5, l32 = lane & 31;
  const int qh = wv >> 1;            // q 32-row group (0..3)
  const int kh = wv & 1;             // QK: key-half (32 keys)
  const int hh = wv & 1;             // PV: h-half (128 h)

  const size_t base = (size_t)nb * T_ * H_;
  const u16* qp = q + base;          // pre-scaled by SCALE_L2E
  const u16* kp = k + base;
  const u16* vtp = vT + ((size_t)n * H_ * B_ + b) * T_;

  __shared__ __align__(16) u16 Ks[2][64][256];   // 64 KB, 5-bit XOR swizzle
  __shared__ __align__(16) u16 Vs[2][64][256];   // 64 KB, packed-4h + 3-bit XOR
  __shared__ __align__(16) u16 Ps[4][32][72];    // 18,432 B (cols 64..67: l-sums)

  const int qrow0 = qt * 128 + qh * 32;
  bf16x8 qf[16];
  #pragma unroll
  for (int kc = 0; kc < 16; kc++)
    qf[kc] = *reinterpret_cast<const bf16x8*>(
        qp + (size_t)(qrow0 + l32) * H_ + kc * 16 + hi * 8);

  f32x16 o[4];
  #pragma unroll
  for (int ot = 0; ot < 4; ot++)
    #pragma unroll
    for (int r = 0; r < 16; r++) o[ot][r] = 0.f;
  float lper[16];
  #pragma unroll
  for (int r = 0; r < 16; r++) lper[r] = 0.f;

  // K staging: 32 DMA instrs (4/wave), each fills 2 rows (512B each).
  auto stage_k = [&](int ktN, int buf) {
    #pragma unroll
    for (int i = 0; i < 4; i++) {
      int idx = wv * 4 + i;
      int row = 2 * idx + hi;
      const u16* src = kp + (size_t)(ktN * 64 + row) * H_ +
                       ((l32 ^ (row & 31)) * 8);
      gload_lds16(src, &Ks[buf][2 * idx][0]);
    }
  };
  // V staging: 32 DMA instrs (4/wave), each fills 2 physical rows.
  auto stage_v = [&](int ktN, int buf) {
    #pragma unroll
    for (int i = 0; i < 4; i++) {
      int idx = wv * 4 + i;
      int p = 2 * idx + hi;
      int u = l32 ^ (p & 7);
      const u16* src = vtp + (size_t)(p * 4 + (u >> 3)) * BT_ +
                       ktN * 64 + (u & 7) * 8;
      gload_lds16(src, &Vs[buf][2 * idx][0]);
    }
  };

  // Prologue: stage tiles 0 and 1; wait only tile 0 (own 8 newest = tile 1).
  stage_k(0, 0); stage_v(0, 0);
  stage_k(1, 1); stage_v(1, 1);
  asm volatile("s_waitcnt vmcnt(8)" ::: "memory");
  __builtin_amdgcn_s_barrier();
  __builtin_amdgcn_sched_barrier(0);

  const int krow = kh * 32 + l32;

  #pragma unroll 1
  for (int kt = 0; kt < 16; kt++) {
    const int c = kt & 1;

    // ---- QK phase: reads Ks[c]
    f32x16 sa, sb;
    #pragma unroll
    for (int r = 0; r < 16; r++) { sa[r] = 0.f; sb[r] = 0.f; }
    __builtin_amdgcn_s_setprio(1);
    #pragma unroll
    for (int kc = 0; kc < 16; kc += 2) {
      bf16x8 kfa = *reinterpret_cast<const bf16x8*>(
          &Ks[c][krow][(((kc * 2 + hi) ^ l32) * 8)]);
      bf16x8 kfb = *reinterpret_cast<const bf16x8*>(
          &Ks[c][krow][(((kc * 2 + 2 + hi) ^ l32) * 8)]);
      sa = mfma32(qf[kc], kfa, sa);
      sb = mfma32(qf[kc + 1], kfb, sb);
    }
    __builtin_amdgcn_s_setprio(0);

    #pragma unroll
    for (int r = 0; r < 16; r++) {
      float p = __builtin_amdgcn_exp2f(sa[r] + sb[r]);  // log2e pre-folded
      lper[r] += p;
      Ps[qh][(r & 3) + 8 * (r >> 2) + 4 * hi][kh * 32 + l32] = f2bf(p);
    }

    // ---- B1: Ps writes visible; Ks[c] readers (all waves) retired.
    asm volatile("s_waitcnt lgkmcnt(0)" ::: "memory");
    __builtin_amdgcn_s_barrier();
    __builtin_amdgcn_sched_barrier(0);

    if (kt < 14) stage_k(kt + 2, c);

    // ---- PV phase: reads Ps + Vs[c]
    bf16x8 pa[4];
    #pragma unroll
    for (int kc2 = 0; kc2 < 4; kc2++)
      pa[kc2] = *reinterpret_cast<const bf16x8*>(
          &Ps[qh][l32][kc2 * 16 + hi * 8]);
    __builtin_amdgcn_s_setprio(1);
    #pragma unroll
    for (int ot = 0; ot < 4; ot++) {
      const int p = hh * 32 + ot * 8 + (l32 >> 2);
      #pragma unroll
      for (int kc2 = 0; kc2 < 4; kc2++) {
        int s = ((l32 & 3) * 8 + kc2 * 2 + hi) ^ (l32 >> 2);
        bf16x8 vf = *reinterpret_cast<const bf16x8*>(&Vs[c][p][s * 8]);
        o[ot] = mfma32(pa[kc2], vf, o[ot]);
      }
    }
    __builtin_amdgcn_s_setprio(0);

    // ---- B2: own K/V(kt+1) landed; Vs[c]/Ps readers retired.
    if (kt < 14) {
      asm volatile("s_waitcnt vmcnt(4)" ::: "memory");
    } else {
      asm volatile("s_waitcnt vmcnt(0)" ::: "memory");
    }
    __builtin_amdgcn_s_barrier();
    __builtin_amdgcn_sched_barrier(0);

    if (kt < 14) stage_v(kt + 2, c);
  }

  #pragma unroll
  for (int r = 0; r < 16; r++) {
    #pragma unroll
    for (int off = 1; off < 32; off <<= 1)
      lper[r] += __shfl_xor(lper[r], off, 64);
  }
  if (l32 == 0) {
    #pragma unroll
    for (int r = 0; r < 16; r++) {
      int row = (r & 3) + 8 * (r >> 2) + 4 * hi;
      *reinterpret_cast<float*>(&Ps[qh][row][64 + 2 * kh]) = lper[r];
    }
  }
  __syncthreads();

  float invl[16];
  #pragma unroll
  for (int r = 0; r < 16; r++) {
    int row = (r & 3) + 8 * (r >> 2) + 4 * hi;
    float l0 = *reinterpret_cast<const float*>(&Ps[qh][row][64]);
    float l1 = *reinterpret_cast<const float*>(&Ps[qh][row][66]);
    invl[r] = 1.0f / (l0 + l1);
  }

  u16* Ew = reinterpret_cast<u16*>(&Ks[0][0][0]) + wv * 1280;   // 8x1280 u16
  const int grow = b * 1024 + qrow0 + l32;
  #pragma unroll
  for (int ot = 0; ot < 4; ot++) {
    #pragma unroll
    for (int r = 0; r < 16; r++) {
      int row = (r & 3) + 8 * (r >> 2) + 4 * hi;
      Ew[row * 40 + l32] = f2bf(o[ot][r] * invl[r]);
    }
    int ht = hh * 4 + ot;
    uint4 v0 = *reinterpret_cast<const uint4*>(&Ew[l32 * 40 + hi * 16]);
    uint4 v1 = *reinterpret_cast<const uint4*>(&Ew[l32 * 40 + hi * 16 + 8]);
    u16* op = obuf + (((size_t)n * 8 + ht) * BT_ + grow) * 32 + hi * 16;
    *reinterpret_cast<uint4*>(op) = v0;
    *reinterpret_cast<uint4*>(op + 8) = v1;
  }
}

// ---------- K4: combine 8 branches (signed) + LayerNorm over H ----------
__global__ __launch_bounds__(256) void combine_ln2_kernel(
    const u16* __restrict__ obuf, const float* __restrict__ w,
    const float* __restrict__ bi, float* __restrict__ out) {
  const int row = blockIdx.x;
  const int h = threadIdx.x;
  float o[8];
  #pragma unroll
  for (int nn = 0; nn < 8; nn++)
    o[nn] = bf1(obuf[(((size_t)nn * 8 + (h >> 5)) * BT_ + row) * 32 + (h & 31)]);
  float re = o[0] - o[1] - o[2] - o[3];
  float im = o[4] + o[5] + o[6] - o[7];
  float sr = re, si = im, sr2 = re * re, si2 = im * im;
  block_reduce4(sr, si, sr2, si2);
  const float inv = 1.0f / H_;
  float mr = sr * inv, mi = si * inv;
  float vr = sr2 * inv - mr * mr, vi = si2 * inv - mi * mi;
  float rr = rsqrtf(vr + EPS), ri = rsqrtf(vi + EPS);
  float ww = w[h], bb = bi[h];
  float2 res;
  res.x = (re - mr) * rr * ww + bb;
  res.y = (im - mi) * ri * ww + bb;
  reinterpret_cast<float2*>(out)[(size_t)row * H_ + h] = res;
}

extern "C" void kernel_launch(void* const* d_in, const int* in_sizes, int n_in,
                              void* d_out, int out_size, void* d_ws, size_t ws_size,
                              hipStream_t stream) {
  const float* x    = (const float*)d_in[0];
  const float* Wq   = (const float*)d_in[1];
  const float* bq   = (const float*)d_in[2];
  const float* Wk   = (const float*)d_in[3];
  const float* bk   = (const float*)d_in[4];
  const float* Wv   = (const float*)d_in[5];
  const float* bv   = (const float*)d_in[6];
  const float* ln1w = (const float*)d_in[7];
  const float* ln1b = (const float*)d_in[8];
  const float* ln2w = (const float*)d_in[9];
  const float* ln2b = (const float*)d_in[10];

  // Workspace (128 MB), lifetime-aliased:
  //  [0,8)  xn  (dead after qkv)  |  [0,32)  obuf (written by attn, after qkv)
  //  [8,11) wT  (dead after qkv)
  //  [32,64) vT ; [64,96) q ; [96,128) k
  char* ws = (char*)d_ws;
  u16* xnr  = (u16*)(ws);
  u16* xni  = (u16*)(ws + (4ull  << 20));
  u16* wTb  = (u16*)(ws + (8ull  << 20));
  u16* obuf = (u16*)(ws);
  u16* vT   = (u16*)(ws + (32ull << 20));
  u16* qbuf = (u16*)(ws + (64ull << 20));
  u16* kbuf = (u16*)(ws + (96ull << 20));

  prep_kernel<<<BT_ + 384, 256, 0, stream>>>(x, ln1w, ln1b, xnr, xni,
                                             Wq, Wk, Wv, wTb);
  qkv_kernel<<<dim3(64, 24), 256, 0, stream>>>(xnr, xni, wTb, bq, bk, bv,
                                               qbuf, kbuf, vT);
  attn_kernel<<<dim3(512), 512, 0, stream>>>(qbuf, kbuf, vT, obuf);
  combine_ln2_kernel<<<BT_, 256, 0, stream>>>(obuf, ln2w, ln2b, (float*)d_out);
}